// Round 10
// baseline (1774.694 us; speedup 1.0000x reference)
//
#include <hip/hip_runtime.h>
#include <stdint.h>

#define H_DIM 128   // hidden width (fixed by weight shapes)
#define D_IN  64    // input feature dim (fixed by weight shapes)

// ---------------- threefry2x32-20, bit-exact with JAX ----------------
__host__ __device__ __forceinline__ void tf2x32(uint32_t k0, uint32_t k1,
    uint32_t x0, uint32_t x1, uint32_t* o0, uint32_t* o1)
{
  uint32_t ks0 = k0, ks1 = k1, ks2 = k0 ^ k1 ^ 0x1BD11BDAu;
  x0 += ks0; x1 += ks1;
#define TFR(r) { x0 += x1; x1 = (x1 << (r)) | (x1 >> (32-(r))); x1 ^= x0; }
  TFR(13) TFR(15) TFR(26) TFR(6)   x0 += ks1; x1 += ks2 + 1u;
  TFR(17) TFR(29) TFR(16) TFR(24)  x0 += ks2; x1 += ks0 + 2u;
  TFR(13) TFR(15) TFR(26) TFR(6)   x0 += ks0; x1 += ks1 + 3u;
  TFR(17) TFR(29) TFR(16) TFR(24)  x0 += ks1; x1 += ks2 + 4u;
  TFR(13) TFR(15) TFR(26) TFR(6)   x0 += ks2; x1 += ks0 + 5u;
#undef TFR
  *o0 = x0; *o1 = x1;
}

__device__ __forceinline__ float bfu(unsigned short u){
  return __uint_as_float(((unsigned int)u) << 16);
}
__device__ __forceinline__ unsigned short f2bf(float f){  // RNE
  unsigned int u = __float_as_uint(f);
  u += 0x7fffu + ((u >> 16) & 1u);
  return (unsigned short)(u >> 16);
}

// canonical weight layout (float offsets) — architecture-fixed
#define WC_WIN 0
#define WC_BIN 8192
#define WC_WC  8320      // + layer*16384
#define WC_BC  41088     // + layer*128
#define WC_G   41344     // + layer*128
#define WC_B   41600     // + layer*128
#define WC_WO  41856
#define WC_BO  42112
#define WC_TOT 42114

// ---------------- per-buffer dtype detector (proven: all groups f32; kept for safety) ----------------
__global__ __launch_bounds__(256) void k_detect(const unsigned short* __restrict__ p,
                                                int limit, int* __restrict__ flag){
  int tid = threadIdx.x;
  int bad = 0;
  for (int i=0;i<16;++i){
    int idx = tid*16 + i;
    if (idx < limit){
      float f = bfu(p[idx]);
      if (!(fabsf(f) < 64.0f)) bad = 1;   // NaN/Inf land here too
    }
  }
  for (int off=32; off; off>>=1) bad |= __shfl_down(bad, off);
  __shared__ int sh[4];
  if ((tid&63)==0) sh[tid>>6] = bad;
  __syncthreads();
  if (tid==0) flag[0] = (sh[0]|sh[1]|sh[2]|sh[3]) ? 0 : 1;
}

// ---------------- init ----------------
__global__ __launch_bounds__(256) void k_zero(int* __restrict__ cnt, int* __restrict__ cur,
                                              double* __restrict__ red, int N){
  int i = blockIdx.x*256 + threadIdx.x;
  if (i < N){ cnt[i] = 0; cur[i] = 0; }
  if (i < 4) red[i] = 0.0;
}

// ---------------- canonicalize weights to f32 (per-group dtype flags) ----------------
__global__ __launch_bounds__(256) void k_wconv(
    const void* __restrict__ W_in, const void* __restrict__ b_in,
    const void* __restrict__ Wc,  const void* __restrict__ bc,
    const void* __restrict__ gam, const void* __restrict__ bet,
    const void* __restrict__ W_o, const void* __restrict__ b_o,
    float* __restrict__ wc, const int* __restrict__ flags)
{
  int idx = blockIdx.x*256 + threadIdx.x;
  if (idx >= WC_TOT) return;
  const void* src; int li; int fsel;
  if      (idx < 8192)  { src=W_in; li=idx;       fsel=1; }
  else if (idx < 8320)  { src=b_in; li=idx-8192;  fsel=1; }
  else if (idx < 41088) { src=Wc;   li=idx-8320;  fsel=2; }
  else if (idx < 41344) { src=bc;   li=idx-41088; fsel=2; }
  else if (idx < 41600) { src=gam;  li=idx-41344; fsel=2; }
  else if (idx < 41856) { src=bet;  li=idx-41600; fsel=2; }
  else if (idx < 42112) { src=W_o;  li=idx-41856; fsel=3; }
  else                  { src=b_o;  li=idx-42112; fsel=3; }
  bool isbf = (flags[fsel] != 0);
  wc[idx] = isbf ? bfu(((const unsigned short*)src)[li]) : ((const float*)src)[li];
}

// ---------------- CSR build ----------------
__global__ __launch_bounds__(256) void k_count(const int* __restrict__ dst, int* __restrict__ cnt, int E){
  int e = blockIdx.x*256 + threadIdx.x;
  if (e < E) atomicAdd(&cnt[dst[e]], 1);
}
__global__ __launch_bounds__(256) void k_scan1(const int* __restrict__ cnt, int* __restrict__ bsum, int N){
  int tid = threadIdx.x;
  int base = blockIdx.x*1024 + tid*4;
  int s = 0;
  #pragma unroll
  for (int j=0;j<4;++j){ int idx = base+j; if (idx < N) s += cnt[idx]; }
  __shared__ int sh[256];
  sh[tid] = s; __syncthreads();
  for (int o=128;o;o>>=1){ if (tid<o) sh[tid]+=sh[tid+o]; __syncthreads(); }
  if (tid==0) bsum[blockIdx.x] = sh[0];
}
__global__ __launch_bounds__(64) void k_scan2(const int* __restrict__ bsum, int* __restrict__ boff,
                                              int nb, int* __restrict__ rowptr, int N){
  if (threadIdx.x==0 && blockIdx.x==0){
    int run = 0;
    for (int b=0;b<nb;++b){ boff[b]=run; run += bsum[b]; }
    rowptr[N] = run;   // == E
  }
}
__global__ __launch_bounds__(256) void k_scan3(const int* __restrict__ cnt, const int* __restrict__ boff,
                                               int* __restrict__ rowptr, float* __restrict__ dinv, int N){
  int tid = threadIdx.x;
  int base = blockIdx.x*1024 + tid*4;
  int a[4]; int tsum = 0;
  #pragma unroll
  for (int j=0;j<4;++j){ int idx=base+j; a[j] = (idx < N) ? cnt[idx] : 0; tsum += a[j]; }
  __shared__ int sh[256];
  sh[tid] = tsum; __syncthreads();
  for (int off=1; off<256; off<<=1){
    int v = 0; if (tid>=off) v = sh[tid-off];
    __syncthreads(); sh[tid] += v; __syncthreads();
  }
  int run = boff[blockIdx.x] + (sh[tid] - tsum);
  #pragma unroll
  for (int j=0;j<4;++j){
    int idx=base+j;
    if (idx < N){
      rowptr[idx] = run;
      dinv[idx] = 1.0f / sqrtf(1.0f + (float)a[j]);
    }
    run += a[j];
  }
}
__global__ __launch_bounds__(256) void k_fill(const int* __restrict__ src, const int* __restrict__ dst,
                                              const int* __restrict__ rowptr, int* __restrict__ cur,
                                              int* __restrict__ csr, int E){
  int e = blockIdx.x*256 + threadIdx.x;
  if (e < E){
    int d = dst[e];
    int p = atomicAdd(&cur[d], 1);
    csr[rowptr[d] + p] = src[e];
  }
}

// ------- GEMM: C[M,128] = A[M,K] @ B[K,128]; A ext (flag dtype) or internal bf16;
//         B canonical f32; C internal bf16; f32 accumulate -------
template<int K, bool EXT, bool RELUBIAS>
__global__ __launch_bounds__(256) void gemm_any(const void* __restrict__ Av,
    const float* __restrict__ Bw, const float* __restrict__ bias,
    unsigned short* __restrict__ C, int M, const int* __restrict__ flagp)
{
  __shared__ float As[64*K];
  const int tid = threadIdx.x;
  const int rowBase = blockIdx.x * 64;
  bool isbf = true;
  if (EXT) isbf = (*flagp != 0);
  #pragma unroll
  for (int it = 0; it < K/16; ++it) {
    int f = tid + it*256;                 // 4-elem group index
    int row = f / (K/4);
    int col = (f - row*(K/4))*4;
    int r = rowBase + row;
    float v0=0.f,v1=0.f,v2=0.f,v3=0.f;
    if (r < M) {
      if (!EXT || isbf) {
        const unsigned int* p = (const unsigned int*)((const unsigned short*)Av + (size_t)r*K + col);
        unsigned int a = p[0], b2 = p[1];
        v0 = __uint_as_float(a<<16);  v1 = __uint_as_float(a & 0xffff0000u);
        v2 = __uint_as_float(b2<<16); v3 = __uint_as_float(b2 & 0xffff0000u);
      } else {
        const float4 q = *(const float4*)((const float*)Av + (size_t)r*K + col);
        v0=q.x; v1=q.y; v2=q.z; v3=q.w;
      }
    }
    As[row*K+col]=v0; As[row*K+col+1]=v1; As[row*K+col+2]=v2; As[row*K+col+3]=v3;
  }
  __syncthreads();
  const int tx = tid & 31, ty = tid >> 5;
  const int c0 = tx*4;
  float acc[8][4];
  #pragma unroll
  for (int i=0;i<8;++i){ acc[i][0]=0.f; acc[i][1]=0.f; acc[i][2]=0.f; acc[i][3]=0.f; }
  #pragma unroll 4
  for (int k = 0; k < K; ++k) {
    float4 bq = *(const float4*)(Bw + (size_t)k*128 + c0);
    #pragma unroll
    for (int i=0;i<8;++i){
      float a = As[(ty*8+i)*K + k];
      acc[i][0] = fmaf(a,bq.x,acc[i][0]);
      acc[i][1] = fmaf(a,bq.y,acc[i][1]);
      acc[i][2] = fmaf(a,bq.z,acc[i][2]);
      acc[i][3] = fmaf(a,bq.w,acc[i][3]);
    }
  }
  float bb0=0.f,bb1=0.f,bb2=0.f,bb3=0.f;
  if (RELUBIAS){ bb0=bias[c0]; bb1=bias[c0+1]; bb2=bias[c0+2]; bb3=bias[c0+3]; }
  #pragma unroll
  for (int i=0;i<8;++i){
    int r = rowBase + ty*8 + i;
    if (r < M){
      float o0=acc[i][0], o1=acc[i][1], o2=acc[i][2], o3=acc[i][3];
      if (RELUBIAS){
        o0=fmaxf(o0+bb0,0.f); o1=fmaxf(o1+bb1,0.f);
        o2=fmaxf(o2+bb2,0.f); o3=fmaxf(o3+bb3,0.f);
      }
      uint2 pk;
      pk.x = (unsigned int)f2bf(o0) | ((unsigned int)f2bf(o1) << 16);
      pk.y = (unsigned int)f2bf(o2) | ((unsigned int)f2bf(o3) << 16);
      *(uint2*)(C + (size_t)r*128 + c0) = pk;
    }
  }
}

// ---- gather: v[n] = sum_in t[s]*dinv[s]*dinv[n] + t[n]*dinv[n]^2 + bc ; graph-LN stats ----
__global__ __launch_bounds__(256) void gcn_gather(const unsigned short* __restrict__ t,
    const int* __restrict__ rowptr, const int* __restrict__ csr,
    const float* __restrict__ dinv, const float* __restrict__ bcw,
    unsigned short* __restrict__ v, double* __restrict__ red, int N)
{
  int node = (int)((blockIdx.x*256u + threadIdx.x) >> 6);
  int lane = threadIdx.x & 63;
  float ls = 0.f, lss = 0.f;
  if (node < N){
    float dn = dinv[node];
    unsigned int tv = ((const unsigned int*)(t + (size_t)node*H_DIM))[lane];
    float ax = __uint_as_float(tv<<16), ay = __uint_as_float(tv & 0xffff0000u);
    float dn2 = dn*dn;
    ax *= dn2; ay *= dn2;
    int e0 = rowptr[node], e1 = rowptr[node+1];
    for (int e = e0; e < e1; ++e){
      int s = csr[e];
      float cf = dinv[s]*dn;
      unsigned int sv = ((const unsigned int*)(t + (size_t)s*H_DIM))[lane];
      ax = fmaf(__uint_as_float(sv<<16),           cf, ax);
      ay = fmaf(__uint_as_float(sv & 0xffff0000u), cf, ay);
    }
    ax += bcw[2*lane]; ay += bcw[2*lane+1];
    unsigned int pk = (unsigned int)f2bf(ax) | ((unsigned int)f2bf(ay) << 16);
    ((unsigned int*)(v + (size_t)node*H_DIM))[lane] = pk;
    ls  = ax + ay;
    lss = ax*ax + ay*ay;
  }
  for (int off=32; off; off>>=1){ ls += __shfl_down(ls, off); lss += __shfl_down(lss, off); }
  __shared__ float ssum[4], ssq[4];
  int wv = threadIdx.x >> 6;
  if (lane==0){ ssum[wv]=ls; ssq[wv]=lss; }
  __syncthreads();
  if (threadIdx.x==0){
    atomicAdd(red,   (double)(ssum[0]+ssum[1]+ssum[2]+ssum[3]));
    atomicAdd(red+1, (double)(ssq[0]+ssq[1]+ssq[2]+ssq[3]));
  }
}

// -------- LayerNorm(graph) + ReLU + dropout, PARTITIONABLE threefry, XOR-fold (R10) --------
// Counter-mode per linear element j: (b0,b1) = tf2x32(key, j>>32 (=0), j&0xffffffff).
// R9 tested bits=b1 (64-bit-combine truncation) -> failed. R10: bits = b0 ^ b1
// (xor-fold of both output words down to 32 bits).
// u = bitcast((bits>>9)|0x3f800000)-1 ; keep u<0.8 ; scale /0.8.
__global__ __launch_bounds__(256) void ln_relu_drop(const unsigned short* __restrict__ v,
    unsigned short* __restrict__ h, const double* __restrict__ red,
    const float* __restrict__ gammaf, const float* __restrict__ betaf,
    uint32_t k0, uint32_t k1, int total, double tot)
{
  int j = blockIdx.x*256 + threadIdx.x;
  if (j >= total) return;
  double S = red[0], Q = red[1];
  double mu_d = S / tot;
  double var_d = Q / tot - mu_d*mu_d;
  if (var_d < 0.0) var_d = 0.0;
  float mu  = (float)mu_d;
  float inv = 1.0f / ((float)sqrt(var_d) + 1e-5f);

  uint32_t b0, b1;
  tf2x32(k0, k1, 0u, (uint32_t)j, &b0, &b1);   // counter hi=0 (j < 2^32), lo=j
  uint32_t bits = b0 ^ b1;                     // R10 single change: xor-fold
  float u = __uint_as_float((bits >> 9) | 0x3f800000u) - 1.0f;

  int c = j & (H_DIM-1);
  float y = fmaf((bfu(v[j]) - mu)*inv, gammaf[c], betaf[c]);
  y = fmaxf(y, 0.f);
  h[j] = f2bf((u < 0.8f) ? (y / 0.8f) : 0.f);
}

// ---------------- out = softmax(h @ W_out + b_out) -> f32 (evidence-locked) ----------------
__global__ __launch_bounds__(256) void out_softmax(const unsigned short* __restrict__ h,
    const float* __restrict__ Wo, const float* __restrict__ bo,
    float2* __restrict__ outv, int N)
{
  int node = (int)((blockIdx.x*256u + threadIdx.x) >> 6);
  int lane = threadIdx.x & 63;
  if (node >= N) return;            // wave-uniform (64 lanes share one node)
  unsigned int hv = ((const unsigned int*)(h + (size_t)node*H_DIM))[lane];
  float h0 = __uint_as_float(hv<<16), h1 = __uint_as_float(hv & 0xffff0000u);
  float4 wq = ((const float4*)Wo)[lane];   // W[2l][0..1], W[2l+1][0..1]
  float d0 = h0*wq.x + h1*wq.z;
  float d1 = h0*wq.y + h1*wq.w;
  for (int off=32; off; off>>=1){ d0 += __shfl_down(d0, off); d1 += __shfl_down(d1, off); }
  if (lane==0){
    d0 += bo[0]; d1 += bo[1];
    float m = fmaxf(d0, d1);
    float e0 = expf(d0 - m), e1 = expf(d1 - m);
    float s = e0 + e1;
    outv[node] = make_float2(e0/s, e1/s);
  }
}

// ---------------- launch ----------------
extern "C" void kernel_launch(void* const* d_in, const int* in_sizes, int n_in,
                              void* d_out, int out_size, void* d_ws, size_t ws_size,
                              hipStream_t stream) {
  (void)n_in; (void)out_size; (void)ws_size;
  const int N = in_sizes[0] / D_IN;     // x is [N, 64]
  const int E = in_sizes[1] / 2;        // edge_index is [2, E]
  const int total = N * H_DIM;
  const double tot = (double)total;

  const int* ei  = (const int*)d_in[1];
  const int* src = ei;
  const int* dst = ei + E;
  char* ws = (char*)d_ws;

  const int nb = (N + 1023) >> 10;      // scan blocks

  // runtime workspace layout, 256B-aligned slabs
  size_t o = 0;
  auto take = [&](size_t bytes)->char*{ char* p = ws + o; o = (o + bytes + 255) & ~(size_t)255; return p; };
  int*    flags  = (int*)   take(4*sizeof(int));   // [x, W_in, Wc, W_out]
  double* red    = (double*)take(4*sizeof(double));
  float*  dinv   = (float*) take((size_t)N*4);
  int*    cnt    = (int*)   take((size_t)N*4);
  int*    cur    = (int*)   take((size_t)N*4);
  int*    rowptr = (int*)   take(((size_t)N+1)*4);
  int*    bsum   = (int*)   take((size_t)nb*4);
  int*    boff   = (int*)   take((size_t)nb*4);
  float*  wc     = (float*) take((size_t)WC_TOT*4);
  int*    csr    = (int*)   take((size_t)E*4);
  unsigned short* actA = (unsigned short*)take((size_t)total*2);
  unsigned short* actB = (unsigned short*)take((size_t)total*2);

  // fold_in(key(1), i) = tf2x32(key=(0,1), counter=threefry_seed(i)=[0,i]) — faithful
  uint32_t k00,k01,k10,k11;
  tf2x32(0u,1u,0u,0u,&k00,&k01);
  tf2x32(0u,1u,0u,1u,&k10,&k11);

  // per-group dtype probes (all resolve f32 on this dataset; kept as cheap insurance)
  int pl0 = in_sizes[0] < 4096 ? in_sizes[0] : 4096;
  int pl1 = in_sizes[2] < 4096 ? in_sizes[2] : 4096;
  int pl2 = in_sizes[4] < 4096 ? in_sizes[4] : 4096;
  int pl3 = in_sizes[8] < 4096 ? in_sizes[8] : 4096;
  k_detect<<<1,256,0,stream>>>((const unsigned short*)d_in[0], pl0, flags+0);
  k_detect<<<1,256,0,stream>>>((const unsigned short*)d_in[2], pl1, flags+1);
  k_detect<<<1,256,0,stream>>>((const unsigned short*)d_in[4], pl2, flags+2);
  k_detect<<<1,256,0,stream>>>((const unsigned short*)d_in[8], pl3, flags+3);

  k_zero  <<<(N+255)/256, 256,0,stream>>>(cnt, cur, red, N);
  k_wconv <<<165, 256,0,stream>>>(d_in[2], d_in[3], d_in[4], d_in[5],
                                  d_in[6], d_in[7], d_in[8], d_in[9], wc, flags);
  k_count <<<(E+255)/256,256,0,stream>>>(dst, cnt, E);
  k_scan1 <<<nb,  256,0,stream>>>(cnt, bsum, N);
  k_scan2 <<<1,    64,0,stream>>>(bsum, boff, nb, rowptr, N);
  k_scan3 <<<nb,  256,0,stream>>>(cnt, boff, rowptr, dinv, N);
  k_fill  <<<(E+255)/256,256,0,stream>>>(src, dst, rowptr, cur, csr, E);

  const int gemmBlocks = (N + 63) / 64;
  const int nodeBlocks = (N + 3) / 4;         // 64 lanes per node, 256 threads
  const int fullBlocks = (total + 255) / 256; // one thread per element

  // A <- relu(x @ W_in + b_in)
  gemm_any<64,true,true><<<gemmBlocks,256,0,stream>>>(d_in[0], wc+WC_WIN, wc+WC_BIN, actA, N, flags+0);

  // layer 0
  gemm_any<128,false,false><<<gemmBlocks,256,0,stream>>>(actA, wc+WC_WC, wc+WC_BIN, actB, N, flags+0);
  gcn_gather<<<nodeBlocks,256,0,stream>>>(actB, rowptr, csr, dinv, wc+WC_BC, actA, red, N);
  ln_relu_drop<<<fullBlocks,256,0,stream>>>(actA, actB, red, wc+WC_G, wc+WC_B, k00, k01, total, tot);

  // layer 1
  gemm_any<128,false,false><<<gemmBlocks,256,0,stream>>>(actB, wc+WC_WC+16384, wc+WC_BIN, actA, N, flags+0);
  gcn_gather<<<nodeBlocks,256,0,stream>>>(actA, rowptr, csr, dinv, wc+WC_BC+128, actB, red+2, N);
  ln_relu_drop<<<fullBlocks,256,0,stream>>>(actB, actA, red+2, wc+WC_G+128, wc+WC_B+128, k10, k11, total, tot);

  // out (f32)
  out_softmax<<<nodeBlocks,256,0,stream>>>(actA, wc+WC_WO, wc+WC_BO, (float2*)d_out, N);
}

// Round 11
// 1760.053 us; speedup vs baseline: 1.0083x; 1.0083x over previous
//
#include <hip/hip_runtime.h>
#include <stdint.h>

#define H_DIM 128   // hidden width (fixed by weight shapes)
#define D_IN  64    // input feature dim (fixed by weight shapes)

// ---------------- threefry2x32-20, bit-exact with JAX ----------------
__host__ __device__ __forceinline__ void tf2x32(uint32_t k0, uint32_t k1,
    uint32_t x0, uint32_t x1, uint32_t* o0, uint32_t* o1)
{
  uint32_t ks0 = k0, ks1 = k1, ks2 = k0 ^ k1 ^ 0x1BD11BDAu;
  x0 += ks0; x1 += ks1;
#define TFR(r) { x0 += x1; x1 = (x1 << (r)) | (x1 >> (32-(r))); x1 ^= x0; }
  TFR(13) TFR(15) TFR(26) TFR(6)   x0 += ks1; x1 += ks2 + 1u;
  TFR(17) TFR(29) TFR(16) TFR(24)  x0 += ks2; x1 += ks0 + 2u;
  TFR(13) TFR(15) TFR(26) TFR(6)   x0 += ks0; x1 += ks1 + 3u;
  TFR(17) TFR(29) TFR(16) TFR(24)  x0 += ks1; x1 += ks2 + 4u;
  TFR(13) TFR(15) TFR(26) TFR(6)   x0 += ks2; x1 += ks0 + 5u;
#undef TFR
  *o0 = x0; *o1 = x1;
}

__device__ __forceinline__ float bfu(unsigned short u){
  return __uint_as_float(((unsigned int)u) << 16);
}
__device__ __forceinline__ unsigned short f2bf(float f){  // RNE
  unsigned int u = __float_as_uint(f);
  u += 0x7fffu + ((u >> 16) & 1u);
  return (unsigned short)(u >> 16);
}

// canonical weight layout (float offsets) — architecture-fixed
#define WC_WIN 0
#define WC_BIN 8192
#define WC_WC  8320      // + layer*16384
#define WC_BC  41088     // + layer*128
#define WC_G   41344     // + layer*128
#define WC_B   41600     // + layer*128
#define WC_WO  41856
#define WC_BO  42112
#define WC_TOT 42114

// ---------------- per-buffer dtype detector (all groups f32 on this dataset; kept) ----------------
__global__ __launch_bounds__(256) void k_detect(const unsigned short* __restrict__ p,
                                                int limit, int* __restrict__ flag){
  int tid = threadIdx.x;
  int bad = 0;
  for (int i=0;i<16;++i){
    int idx = tid*16 + i;
    if (idx < limit){
      float f = bfu(p[idx]);
      if (!(fabsf(f) < 64.0f)) bad = 1;
    }
  }
  for (int off=32; off; off>>=1) bad |= __shfl_down(bad, off);
  __shared__ int sh[4];
  if ((tid&63)==0) sh[tid>>6] = bad;
  __syncthreads();
  if (tid==0) flag[0] = (sh[0]|sh[1]|sh[2]|sh[3]) ? 0 : 1;
}

// ---------------- init ----------------
__global__ __launch_bounds__(256) void k_zero(int* __restrict__ cnt, int* __restrict__ cur,
                                              double* __restrict__ red, int N){
  int i = blockIdx.x*256 + threadIdx.x;
  if (i < N){ cnt[i] = 0; cur[i] = 0; }
  if (i < 4) red[i] = 0.0;
}

// ---------------- canonicalize weights to f32 (per-group dtype flags) ----------------
__global__ __launch_bounds__(256) void k_wconv(
    const void* __restrict__ W_in, const void* __restrict__ b_in,
    const void* __restrict__ Wc,  const void* __restrict__ bc,
    const void* __restrict__ gam, const void* __restrict__ bet,
    const void* __restrict__ W_o, const void* __restrict__ b_o,
    float* __restrict__ wc, const int* __restrict__ flags)
{
  int idx = blockIdx.x*256 + threadIdx.x;
  if (idx >= WC_TOT) return;
  const void* src; int li; int fsel;
  if      (idx < 8192)  { src=W_in; li=idx;       fsel=1; }
  else if (idx < 8320)  { src=b_in; li=idx-8192;  fsel=1; }
  else if (idx < 41088) { src=Wc;   li=idx-8320;  fsel=2; }
  else if (idx < 41344) { src=bc;   li=idx-41088; fsel=2; }
  else if (idx < 41600) { src=gam;  li=idx-41344; fsel=2; }
  else if (idx < 41856) { src=bet;  li=idx-41600; fsel=2; }
  else if (idx < 42112) { src=W_o;  li=idx-41856; fsel=3; }
  else                  { src=b_o;  li=idx-42112; fsel=3; }
  bool isbf = (flags[fsel] != 0);
  wc[idx] = isbf ? bfu(((const unsigned short*)src)[li]) : ((const float*)src)[li];
}

// ---------------- CSR build ----------------
__global__ __launch_bounds__(256) void k_count(const int* __restrict__ dst, int* __restrict__ cnt, int E){
  int e = blockIdx.x*256 + threadIdx.x;
  if (e < E) atomicAdd(&cnt[dst[e]], 1);
}
__global__ __launch_bounds__(256) void k_scan1(const int* __restrict__ cnt, int* __restrict__ bsum, int N){
  int tid = threadIdx.x;
  int base = blockIdx.x*1024 + tid*4;
  int s = 0;
  #pragma unroll
  for (int j=0;j<4;++j){ int idx = base+j; if (idx < N) s += cnt[idx]; }
  __shared__ int sh[256];
  sh[tid] = s; __syncthreads();
  for (int o=128;o;o>>=1){ if (tid<o) sh[tid]+=sh[tid+o]; __syncthreads(); }
  if (tid==0) bsum[blockIdx.x] = sh[0];
}
__global__ __launch_bounds__(64) void k_scan2(const int* __restrict__ bsum, int* __restrict__ boff,
                                              int nb, int* __restrict__ rowptr, int N){
  if (threadIdx.x==0 && blockIdx.x==0){
    int run = 0;
    for (int b=0;b<nb;++b){ boff[b]=run; run += bsum[b]; }
    rowptr[N] = run;   // == E
  }
}
__global__ __launch_bounds__(256) void k_scan3(const int* __restrict__ cnt, const int* __restrict__ boff,
                                               int* __restrict__ rowptr, float* __restrict__ dinv, int N){
  int tid = threadIdx.x;
  int base = blockIdx.x*1024 + tid*4;
  int a[4]; int tsum = 0;
  #pragma unroll
  for (int j=0;j<4;++j){ int idx=base+j; a[j] = (idx < N) ? cnt[idx] : 0; tsum += a[j]; }
  __shared__ int sh[256];
  sh[tid] = tsum; __syncthreads();
  for (int off=1; off<256; off<<=1){
    int v = 0; if (tid>=off) v = sh[tid-off];
    __syncthreads(); sh[tid] += v; __syncthreads();
  }
  int run = boff[blockIdx.x] + (sh[tid] - tsum);
  #pragma unroll
  for (int j=0;j<4;++j){
    int idx=base+j;
    if (idx < N){
      rowptr[idx] = run;
      dinv[idx] = 1.0f / sqrtf(1.0f + (float)a[j]);
    }
    run += a[j];
  }
}
__global__ __launch_bounds__(256) void k_fill(const int* __restrict__ src, const int* __restrict__ dst,
                                              const int* __restrict__ rowptr, int* __restrict__ cur,
                                              int* __restrict__ csr, int E){
  int e = blockIdx.x*256 + threadIdx.x;
  if (e < E){
    int d = dst[e];
    int p = atomicAdd(&cur[d], 1);
    csr[rowptr[d] + p] = src[e];
  }
}

// ------- GEMM: C[M,128] = A[M,K] @ B[K,128]; A ext (flag dtype) or internal bf16;
//         B canonical f32; C internal bf16; f32 accumulate -------
template<int K, bool EXT, bool RELUBIAS>
__global__ __launch_bounds__(256) void gemm_any(const void* __restrict__ Av,
    const float* __restrict__ Bw, const float* __restrict__ bias,
    unsigned short* __restrict__ C, int M, const int* __restrict__ flagp)
{
  __shared__ float As[64*K];
  const int tid = threadIdx.x;
  const int rowBase = blockIdx.x * 64;
  bool isbf = true;
  if (EXT) isbf = (*flagp != 0);
  #pragma unroll
  for (int it = 0; it < K/16; ++it) {
    int f = tid + it*256;                 // 4-elem group index
    int row = f / (K/4);
    int col = (f - row*(K/4))*4;
    int r = rowBase + row;
    float v0=0.f,v1=0.f,v2=0.f,v3=0.f;
    if (r < M) {
      if (!EXT || isbf) {
        const unsigned int* p = (const unsigned int*)((const unsigned short*)Av + (size_t)r*K + col);
        unsigned int a = p[0], b2 = p[1];
        v0 = __uint_as_float(a<<16);  v1 = __uint_as_float(a & 0xffff0000u);
        v2 = __uint_as_float(b2<<16); v3 = __uint_as_float(b2 & 0xffff0000u);
      } else {
        const float4 q = *(const float4*)((const float*)Av + (size_t)r*K + col);
        v0=q.x; v1=q.y; v2=q.z; v3=q.w;
      }
    }
    As[row*K+col]=v0; As[row*K+col+1]=v1; As[row*K+col+2]=v2; As[row*K+col+3]=v3;
  }
  __syncthreads();
  const int tx = tid & 31, ty = tid >> 5;
  const int c0 = tx*4;
  float acc[8][4];
  #pragma unroll
  for (int i=0;i<8;++i){ acc[i][0]=0.f; acc[i][1]=0.f; acc[i][2]=0.f; acc[i][3]=0.f; }
  #pragma unroll 4
  for (int k = 0; k < K; ++k) {
    float4 bq = *(const float4*)(Bw + (size_t)k*128 + c0);
    #pragma unroll
    for (int i=0;i<8;++i){
      float a = As[(ty*8+i)*K + k];
      acc[i][0] = fmaf(a,bq.x,acc[i][0]);
      acc[i][1] = fmaf(a,bq.y,acc[i][1]);
      acc[i][2] = fmaf(a,bq.z,acc[i][2]);
      acc[i][3] = fmaf(a,bq.w,acc[i][3]);
    }
  }
  float bb0=0.f,bb1=0.f,bb2=0.f,bb3=0.f;
  if (RELUBIAS){ bb0=bias[c0]; bb1=bias[c0+1]; bb2=bias[c0+2]; bb3=bias[c0+3]; }
  #pragma unroll
  for (int i=0;i<8;++i){
    int r = rowBase + ty*8 + i;
    if (r < M){
      float o0=acc[i][0], o1=acc[i][1], o2=acc[i][2], o3=acc[i][3];
      if (RELUBIAS){
        o0=fmaxf(o0+bb0,0.f); o1=fmaxf(o1+bb1,0.f);
        o2=fmaxf(o2+bb2,0.f); o3=fmaxf(o3+bb3,0.f);
      }
      uint2 pk;
      pk.x = (unsigned int)f2bf(o0) | ((unsigned int)f2bf(o1) << 16);
      pk.y = (unsigned int)f2bf(o2) | ((unsigned int)f2bf(o3) << 16);
      *(uint2*)(C + (size_t)r*128 + c0) = pk;
    }
  }
}

// ---- gather (R11: 8-way unrolled edge loop for memory-level parallelism) ----
// v[n] = sum_in t[s]*dinv[s]*dinv[n] + t[n]*dinv[n]^2 + bc ; graph-LN stats.
// R10 counters: 616us, VALUBusy 6.7%, hbm 367 GB/s -> latency-bound on the
// serial csr->dinv->row dependent chain. Unroll-8 puts 8 row-loads in flight.
__global__ __launch_bounds__(256) void gcn_gather(const unsigned short* __restrict__ t,
    const int* __restrict__ rowptr, const int* __restrict__ csr,
    const float* __restrict__ dinv, const float* __restrict__ bcw,
    unsigned short* __restrict__ v, double* __restrict__ red, int N)
{
  int node = (int)((blockIdx.x*256u + threadIdx.x) >> 6);
  int lane = threadIdx.x & 63;
  float ls = 0.f, lss = 0.f;
  if (node < N){
    float dn = dinv[node];
    unsigned int tv = ((const unsigned int*)(t + (size_t)node*H_DIM))[lane];
    float ax = __uint_as_float(tv<<16), ay = __uint_as_float(tv & 0xffff0000u);
    float dn2 = dn*dn;
    ax *= dn2; ay *= dn2;
    int e0 = rowptr[node], e1 = rowptr[node+1];
    int e = e0;
    // main: 8 edges per trip, all loads issued before any use
    for (; e + 8 <= e1; e += 8){
      int s[8];
      #pragma unroll
      for (int q=0;q<8;++q) s[q] = csr[e+q];
      float cf[8];
      #pragma unroll
      for (int q=0;q<8;++q) cf[q] = dinv[s[q]];
      unsigned int rv[8];
      #pragma unroll
      for (int q=0;q<8;++q) rv[q] = ((const unsigned int*)(t + (size_t)s[q]*H_DIM))[lane];
      #pragma unroll
      for (int q=0;q<8;++q){
        float c = cf[q]*dn;
        ax = fmaf(__uint_as_float(rv[q]<<16),           c, ax);
        ay = fmaf(__uint_as_float(rv[q] & 0xffff0000u), c, ay);
      }
    }
    // tail
    for (; e < e1; ++e){
      int s = csr[e];
      float c = dinv[s]*dn;
      unsigned int sv = ((const unsigned int*)(t + (size_t)s*H_DIM))[lane];
      ax = fmaf(__uint_as_float(sv<<16),           c, ax);
      ay = fmaf(__uint_as_float(sv & 0xffff0000u), c, ay);
    }
    ax += bcw[2*lane]; ay += bcw[2*lane+1];
    unsigned int pk = (unsigned int)f2bf(ax) | ((unsigned int)f2bf(ay) << 16);
    ((unsigned int*)(v + (size_t)node*H_DIM))[lane] = pk;
    ls  = ax + ay;
    lss = ax*ax + ay*ay;
  }
  for (int off=32; off; off>>=1){ ls += __shfl_down(ls, off); lss += __shfl_down(lss, off); }
  __shared__ float ssum[4], ssq[4];
  int wv = threadIdx.x >> 6;
  if (lane==0){ ssum[wv]=ls; ssq[wv]=lss; }
  __syncthreads();
  if (threadIdx.x==0){
    atomicAdd(red,   (double)(ssum[0]+ssum[1]+ssum[2]+ssum[3]));
    atomicAdd(red+1, (double)(ssq[0]+ssq[1]+ssq[2]+ssq[3]));
  }
}

// -------- LayerNorm(graph) + ReLU + dropout (partitionable threefry, XOR-fold — VERIFIED R10) --------
__global__ __launch_bounds__(256) void ln_relu_drop(const unsigned short* __restrict__ v,
    unsigned short* __restrict__ h, const double* __restrict__ red,
    const float* __restrict__ gammaf, const float* __restrict__ betaf,
    uint32_t k0, uint32_t k1, int total, double tot)
{
  int j = blockIdx.x*256 + threadIdx.x;
  if (j >= total) return;
  double S = red[0], Q = red[1];
  double mu_d = S / tot;
  double var_d = Q / tot - mu_d*mu_d;
  if (var_d < 0.0) var_d = 0.0;
  float mu  = (float)mu_d;
  float inv = 1.0f / ((float)sqrt(var_d) + 1e-5f);

  uint32_t b0, b1;
  tf2x32(k0, k1, 0u, (uint32_t)j, &b0, &b1);   // counter hi=0, lo=j
  uint32_t bits = b0 ^ b1;                     // xor-fold (verified)
  float u = __uint_as_float((bits >> 9) | 0x3f800000u) - 1.0f;

  int c = j & (H_DIM-1);
  float y = fmaf((bfu(v[j]) - mu)*inv, gammaf[c], betaf[c]);
  y = fmaxf(y, 0.f);
  h[j] = f2bf((u < 0.8f) ? (y / 0.8f) : 0.f);
}

// ---------------- out = softmax(h @ W_out + b_out) -> f32 ----------------
__global__ __launch_bounds__(256) void out_softmax(const unsigned short* __restrict__ h,
    const float* __restrict__ Wo, const float* __restrict__ bo,
    float2* __restrict__ outv, int N)
{
  int node = (int)((blockIdx.x*256u + threadIdx.x) >> 6);
  int lane = threadIdx.x & 63;
  if (node >= N) return;
  unsigned int hv = ((const unsigned int*)(h + (size_t)node*H_DIM))[lane];
  float h0 = __uint_as_float(hv<<16), h1 = __uint_as_float(hv & 0xffff0000u);
  float4 wq = ((const float4*)Wo)[lane];
  float d0 = h0*wq.x + h1*wq.z;
  float d1 = h0*wq.y + h1*wq.w;
  for (int off=32; off; off>>=1){ d0 += __shfl_down(d0, off); d1 += __shfl_down(d1, off); }
  if (lane==0){
    d0 += bo[0]; d1 += bo[1];
    float m = fmaxf(d0, d1);
    float e0 = expf(d0 - m), e1 = expf(d1 - m);
    float s = e0 + e1;
    outv[node] = make_float2(e0/s, e1/s);
  }
}

// ---------------- launch ----------------
extern "C" void kernel_launch(void* const* d_in, const int* in_sizes, int n_in,
                              void* d_out, int out_size, void* d_ws, size_t ws_size,
                              hipStream_t stream) {
  (void)n_in; (void)out_size; (void)ws_size;
  const int N = in_sizes[0] / D_IN;     // x is [N, 64]
  const int E = in_sizes[1] / 2;        // edge_index is [2, E]
  const int total = N * H_DIM;
  const double tot = (double)total;

  const int* ei  = (const int*)d_in[1];
  const int* src = ei;
  const int* dst = ei + E;
  char* ws = (char*)d_ws;

  const int nb = (N + 1023) >> 10;      // scan blocks

  // runtime workspace layout, 256B-aligned slabs
  size_t o = 0;
  auto take = [&](size_t bytes)->char*{ char* p = ws + o; o = (o + bytes + 255) & ~(size_t)255; return p; };
  int*    flags  = (int*)   take(4*sizeof(int));   // [x, W_in, Wc, W_out]
  double* red    = (double*)take(4*sizeof(double));
  float*  dinv   = (float*) take((size_t)N*4);
  int*    cnt    = (int*)   take((size_t)N*4);
  int*    cur    = (int*)   take((size_t)N*4);
  int*    rowptr = (int*)   take(((size_t)N+1)*4);
  int*    bsum   = (int*)   take((size_t)nb*4);
  int*    boff   = (int*)   take((size_t)nb*4);
  float*  wc     = (float*) take((size_t)WC_TOT*4);
  int*    csr    = (int*)   take((size_t)E*4);
  unsigned short* actA = (unsigned short*)take((size_t)total*2);
  unsigned short* actB = (unsigned short*)take((size_t)total*2);

  // fold_in(key(1), i) = tf2x32(key=(0,1), counter=[0,i]) — verified
  uint32_t k00,k01,k10,k11;
  tf2x32(0u,1u,0u,0u,&k00,&k01);
  tf2x32(0u,1u,0u,1u,&k10,&k11);

  int pl0 = in_sizes[0] < 4096 ? in_sizes[0] : 4096;
  int pl1 = in_sizes[2] < 4096 ? in_sizes[2] : 4096;
  int pl2 = in_sizes[4] < 4096 ? in_sizes[4] : 4096;
  int pl3 = in_sizes[8] < 4096 ? in_sizes[8] : 4096;
  k_detect<<<1,256,0,stream>>>((const unsigned short*)d_in[0], pl0, flags+0);
  k_detect<<<1,256,0,stream>>>((const unsigned short*)d_in[2], pl1, flags+1);
  k_detect<<<1,256,0,stream>>>((const unsigned short*)d_in[4], pl2, flags+2);
  k_detect<<<1,256,0,stream>>>((const unsigned short*)d_in[8], pl3, flags+3);

  k_zero  <<<(N+255)/256, 256,0,stream>>>(cnt, cur, red, N);
  k_wconv <<<165, 256,0,stream>>>(d_in[2], d_in[3], d_in[4], d_in[5],
                                  d_in[6], d_in[7], d_in[8], d_in[9], wc, flags);
  k_count <<<(E+255)/256,256,0,stream>>>(dst, cnt, E);
  k_scan1 <<<nb,  256,0,stream>>>(cnt, bsum, N);
  k_scan2 <<<1,    64,0,stream>>>(bsum, boff, nb, rowptr, N);
  k_scan3 <<<nb,  256,0,stream>>>(cnt, boff, rowptr, dinv, N);
  k_fill  <<<(E+255)/256,256,0,stream>>>(src, dst, rowptr, cur, csr, E);

  const int gemmBlocks = (N + 63) / 64;
  const int nodeBlocks = (N + 3) / 4;         // 64 lanes per node
  const int fullBlocks = (total + 255) / 256; // one thread per element

  // A <- relu(x @ W_in + b_in)
  gemm_any<64,true,true><<<gemmBlocks,256,0,stream>>>(d_in[0], wc+WC_WIN, wc+WC_BIN, actA, N, flags+0);

  // layer 0
  gemm_any<128,false,false><<<gemmBlocks,256,0,stream>>>(actA, wc+WC_WC, wc+WC_BIN, actB, N, flags+0);
  gcn_gather<<<nodeBlocks,256,0,stream>>>(actB, rowptr, csr, dinv, wc+WC_BC, actA, red, N);
  ln_relu_drop<<<fullBlocks,256,0,stream>>>(actA, actB, red, wc+WC_G, wc+WC_B, k00, k01, total, tot);

  // layer 1
  gemm_any<128,false,false><<<gemmBlocks,256,0,stream>>>(actB, wc+WC_WC+16384, wc+WC_BIN, actA, N, flags+0);
  gcn_gather<<<nodeBlocks,256,0,stream>>>(actA, rowptr, csr, dinv, wc+WC_BC+128, actB, red+2, N);
  ln_relu_drop<<<fullBlocks,256,0,stream>>>(actB, actA, red+2, wc+WC_G+128, wc+WC_B+128, k10, k11, total, tot);

  // out (f32)
  out_softmax<<<nodeBlocks,256,0,stream>>>(actA, wc+WC_WO, wc+WC_BO, (float2*)d_out, N);
}

// Round 12
// 746.224 us; speedup vs baseline: 2.3782x; 2.3586x over previous
//
#include <hip/hip_runtime.h>
#include <stdint.h>

#define H_DIM 128   // hidden width (fixed by weight shapes)
#define D_IN  64    // input feature dim (fixed by weight shapes)

// ---------------- threefry2x32-20, bit-exact with JAX ----------------
__host__ __device__ __forceinline__ void tf2x32(uint32_t k0, uint32_t k1,
    uint32_t x0, uint32_t x1, uint32_t* o0, uint32_t* o1)
{
  uint32_t ks0 = k0, ks1 = k1, ks2 = k0 ^ k1 ^ 0x1BD11BDAu;
  x0 += ks0; x1 += ks1;
#define TFR(r) { x0 += x1; x1 = (x1 << (r)) | (x1 >> (32-(r))); x1 ^= x0; }
  TFR(13) TFR(15) TFR(26) TFR(6)   x0 += ks1; x1 += ks2 + 1u;
  TFR(17) TFR(29) TFR(16) TFR(24)  x0 += ks2; x1 += ks0 + 2u;
  TFR(13) TFR(15) TFR(26) TFR(6)   x0 += ks0; x1 += ks1 + 3u;
  TFR(17) TFR(29) TFR(16) TFR(24)  x0 += ks1; x1 += ks2 + 4u;
  TFR(13) TFR(15) TFR(26) TFR(6)   x0 += ks2; x1 += ks0 + 5u;
#undef TFR
  *o0 = x0; *o1 = x1;
}

__device__ __forceinline__ float bfu(unsigned short u){
  return __uint_as_float(((unsigned int)u) << 16);
}
__device__ __forceinline__ unsigned short f2bf(float f){  // RNE
  unsigned int u = __float_as_uint(f);
  u += 0x7fffu + ((u >> 16) & 1u);
  return (unsigned short)(u >> 16);
}

// canonical weight layout (float offsets) — architecture-fixed
#define WC_WIN 0
#define WC_BIN 8192
#define WC_WC  8320      // + layer*16384
#define WC_BC  41088     // + layer*128
#define WC_G   41344     // + layer*128
#define WC_B   41600     // + layer*128
#define WC_WO  41856
#define WC_BO  42112
#define WC_TOT 42114

// ---------------- per-buffer dtype detector (all groups f32 on this dataset; kept) ----------------
__global__ __launch_bounds__(256) void k_detect(const unsigned short* __restrict__ p,
                                                int limit, int* __restrict__ flag){
  int tid = threadIdx.x;
  int bad = 0;
  for (int i=0;i<16;++i){
    int idx = tid*16 + i;
    if (idx < limit){
      float f = bfu(p[idx]);
      if (!(fabsf(f) < 64.0f)) bad = 1;
    }
  }
  for (int off=32; off; off>>=1) bad |= __shfl_down(bad, off);
  __shared__ int sh[4];
  if ((tid&63)==0) sh[tid>>6] = bad;
  __syncthreads();
  if (tid==0) flag[0] = (sh[0]|sh[1]|sh[2]|sh[3]) ? 0 : 1;
}

// ---------------- init ----------------
__global__ __launch_bounds__(256) void k_zero(int* __restrict__ cnt, int* __restrict__ cur, int N){
  int i = blockIdx.x*256 + threadIdx.x;
  if (i < N){ cnt[i] = 0; cur[i] = 0; }
}

// ---------------- canonicalize weights to f32 (per-group dtype flags) ----------------
__global__ __launch_bounds__(256) void k_wconv(
    const void* __restrict__ W_in, const void* __restrict__ b_in,
    const void* __restrict__ Wc,  const void* __restrict__ bc,
    const void* __restrict__ gam, const void* __restrict__ bet,
    const void* __restrict__ W_o, const void* __restrict__ b_o,
    float* __restrict__ wc, const int* __restrict__ flags)
{
  int idx = blockIdx.x*256 + threadIdx.x;
  if (idx >= WC_TOT) return;
  const void* src; int li; int fsel;
  if      (idx < 8192)  { src=W_in; li=idx;       fsel=1; }
  else if (idx < 8320)  { src=b_in; li=idx-8192;  fsel=1; }
  else if (idx < 41088) { src=Wc;   li=idx-8320;  fsel=2; }
  else if (idx < 41344) { src=bc;   li=idx-41088; fsel=2; }
  else if (idx < 41600) { src=gam;  li=idx-41344; fsel=2; }
  else if (idx < 41856) { src=bet;  li=idx-41600; fsel=2; }
  else if (idx < 42112) { src=W_o;  li=idx-41856; fsel=3; }
  else                  { src=b_o;  li=idx-42112; fsel=3; }
  bool isbf = (flags[fsel] != 0);
  wc[idx] = isbf ? bfu(((const unsigned short*)src)[li]) : ((const float*)src)[li];
}

// ---------------- CSR build ----------------
__global__ __launch_bounds__(256) void k_count(const int* __restrict__ dst, int* __restrict__ cnt, int E){
  int e = blockIdx.x*256 + threadIdx.x;
  if (e < E) atomicAdd(&cnt[dst[e]], 1);
}
__global__ __launch_bounds__(256) void k_scan1(const int* __restrict__ cnt, int* __restrict__ bsum, int N){
  int tid = threadIdx.x;
  int base = blockIdx.x*1024 + tid*4;
  int s = 0;
  #pragma unroll
  for (int j=0;j<4;++j){ int idx = base+j; if (idx < N) s += cnt[idx]; }
  __shared__ int sh[256];
  sh[tid] = s; __syncthreads();
  for (int o=128;o;o>>=1){ if (tid<o) sh[tid]+=sh[tid+o]; __syncthreads(); }
  if (tid==0) bsum[blockIdx.x] = sh[0];
}
__global__ __launch_bounds__(64) void k_scan2(const int* __restrict__ bsum, int* __restrict__ boff,
                                              int nb, int* __restrict__ rowptr, int N){
  if (threadIdx.x==0 && blockIdx.x==0){
    int run = 0;
    for (int b=0;b<nb;++b){ boff[b]=run; run += bsum[b]; }
    rowptr[N] = run;   // == E
  }
}
__global__ __launch_bounds__(256) void k_scan3(const int* __restrict__ cnt, const int* __restrict__ boff,
                                               int* __restrict__ rowptr, float* __restrict__ dinv, int N){
  int tid = threadIdx.x;
  int base = blockIdx.x*1024 + tid*4;
  int a[4]; int tsum = 0;
  #pragma unroll
  for (int j=0;j<4;++j){ int idx=base+j; a[j] = (idx < N) ? cnt[idx] : 0; tsum += a[j]; }
  __shared__ int sh[256];
  sh[tid] = tsum; __syncthreads();
  for (int off=1; off<256; off<<=1){
    int v = 0; if (tid>=off) v = sh[tid-off];
    __syncthreads(); sh[tid] += v; __syncthreads();
  }
  int run = boff[blockIdx.x] + (sh[tid] - tsum);
  #pragma unroll
  for (int j=0;j<4;++j){
    int idx=base+j;
    if (idx < N){
      rowptr[idx] = run;
      dinv[idx] = 1.0f / sqrtf(1.0f + (float)a[j]);
    }
    run += a[j];
  }
}
__global__ __launch_bounds__(256) void k_fill(const int* __restrict__ src, const int* __restrict__ dst,
                                              const int* __restrict__ rowptr, int* __restrict__ cur,
                                              int* __restrict__ csr, int E){
  int e = blockIdx.x*256 + threadIdx.x;
  if (e < E){
    int d = dst[e];
    int p = atomicAdd(&cur[d], 1);
    csr[rowptr[d] + p] = src[e];
  }
}

// ------- GEMM: C[M,128] = A[M,K] @ B[K,128]; A ext (flag dtype) or internal bf16;
//         B canonical f32; C internal bf16; f32 accumulate -------
template<int K, bool EXT, bool RELUBIAS>
__global__ __launch_bounds__(256) void gemm_any(const void* __restrict__ Av,
    const float* __restrict__ Bw, const float* __restrict__ bias,
    unsigned short* __restrict__ C, int M, const int* __restrict__ flagp)
{
  __shared__ float As[64*K];
  const int tid = threadIdx.x;
  const int rowBase = blockIdx.x * 64;
  bool isbf = true;
  if (EXT) isbf = (*flagp != 0);
  #pragma unroll
  for (int it = 0; it < K/16; ++it) {
    int f = tid + it*256;                 // 4-elem group index
    int row = f / (K/4);
    int col = (f - row*(K/4))*4;
    int r = rowBase + row;
    float v0=0.f,v1=0.f,v2=0.f,v3=0.f;
    if (r < M) {
      if (!EXT || isbf) {
        const unsigned int* p = (const unsigned int*)((const unsigned short*)Av + (size_t)r*K + col);
        unsigned int a = p[0], b2 = p[1];
        v0 = __uint_as_float(a<<16);  v1 = __uint_as_float(a & 0xffff0000u);
        v2 = __uint_as_float(b2<<16); v3 = __uint_as_float(b2 & 0xffff0000u);
      } else {
        const float4 q = *(const float4*)((const float*)Av + (size_t)r*K + col);
        v0=q.x; v1=q.y; v2=q.z; v3=q.w;
      }
    }
    As[row*K+col]=v0; As[row*K+col+1]=v1; As[row*K+col+2]=v2; As[row*K+col+3]=v3;
  }
  __syncthreads();
  const int tx = tid & 31, ty = tid >> 5;
  const int c0 = tx*4;
  float acc[8][4];
  #pragma unroll
  for (int i=0;i<8;++i){ acc[i][0]=0.f; acc[i][1]=0.f; acc[i][2]=0.f; acc[i][3]=0.f; }
  #pragma unroll 4
  for (int k = 0; k < K; ++k) {
    float4 bq = *(const float4*)(Bw + (size_t)k*128 + c0);
    #pragma unroll
    for (int i=0;i<8;++i){
      float a = As[(ty*8+i)*K + k];
      acc[i][0] = fmaf(a,bq.x,acc[i][0]);
      acc[i][1] = fmaf(a,bq.y,acc[i][1]);
      acc[i][2] = fmaf(a,bq.z,acc[i][2]);
      acc[i][3] = fmaf(a,bq.w,acc[i][3]);
    }
  }
  float bb0=0.f,bb1=0.f,bb2=0.f,bb3=0.f;
  if (RELUBIAS){ bb0=bias[c0]; bb1=bias[c0+1]; bb2=bias[c0+2]; bb3=bias[c0+3]; }
  #pragma unroll
  for (int i=0;i<8;++i){
    int r = rowBase + ty*8 + i;
    if (r < M){
      float o0=acc[i][0], o1=acc[i][1], o2=acc[i][2], o3=acc[i][3];
      if (RELUBIAS){
        o0=fmaxf(o0+bb0,0.f); o1=fmaxf(o1+bb1,0.f);
        o2=fmaxf(o2+bb2,0.f); o3=fmaxf(o3+bb3,0.f);
      }
      uint2 pk;
      pk.x = (unsigned int)f2bf(o0) | ((unsigned int)f2bf(o1) << 16);
      pk.y = (unsigned int)f2bf(o2) | ((unsigned int)f2bf(o3) << 16);
      *(uint2*)(C + (size_t)r*128 + c0) = pk;
    }
  }
}

// ---- gather (R12: NO global atomics — per-block partial stats to `part`) ----
// R10/R11 post-mortem: 611us invariant under unroll-8 => not MLP-bound; the
// 50k same-address device-scope f64 atomicAdds (~12ns serialized each) ARE the
// 600us. Partials are now plain stores; k_reduce sums them.
__global__ __launch_bounds__(256) void gcn_gather(const unsigned short* __restrict__ t,
    const int* __restrict__ rowptr, const int* __restrict__ csr,
    const float* __restrict__ dinv, const float* __restrict__ bcw,
    unsigned short* __restrict__ v, double* __restrict__ part, int N)
{
  int node = (int)((blockIdx.x*256u + threadIdx.x) >> 6);
  int lane = threadIdx.x & 63;
  float ls = 0.f, lss = 0.f;
  if (node < N){
    float dn = dinv[node];
    unsigned int tv = ((const unsigned int*)(t + (size_t)node*H_DIM))[lane];
    float ax = __uint_as_float(tv<<16), ay = __uint_as_float(tv & 0xffff0000u);
    float dn2 = dn*dn;
    ax *= dn2; ay *= dn2;
    int e0 = rowptr[node], e1 = rowptr[node+1];
    int e = e0;
    for (; e + 8 <= e1; e += 8){
      int s[8];
      #pragma unroll
      for (int q=0;q<8;++q) s[q] = csr[e+q];
      float cf[8];
      #pragma unroll
      for (int q=0;q<8;++q) cf[q] = dinv[s[q]];
      unsigned int rv[8];
      #pragma unroll
      for (int q=0;q<8;++q) rv[q] = ((const unsigned int*)(t + (size_t)s[q]*H_DIM))[lane];
      #pragma unroll
      for (int q=0;q<8;++q){
        float c = cf[q]*dn;
        ax = fmaf(__uint_as_float(rv[q]<<16),           c, ax);
        ay = fmaf(__uint_as_float(rv[q] & 0xffff0000u), c, ay);
      }
    }
    for (; e < e1; ++e){
      int s = csr[e];
      float c = dinv[s]*dn;
      unsigned int sv = ((const unsigned int*)(t + (size_t)s*H_DIM))[lane];
      ax = fmaf(__uint_as_float(sv<<16),           c, ax);
      ay = fmaf(__uint_as_float(sv & 0xffff0000u), c, ay);
    }
    ax += bcw[2*lane]; ay += bcw[2*lane+1];
    unsigned int pk = (unsigned int)f2bf(ax) | ((unsigned int)f2bf(ay) << 16);
    ((unsigned int*)(v + (size_t)node*H_DIM))[lane] = pk;
    ls  = ax + ay;
    lss = ax*ax + ay*ay;
  }
  for (int off=32; off; off>>=1){ ls += __shfl_down(ls, off); lss += __shfl_down(lss, off); }
  __shared__ float ssum[4], ssq[4];
  int wv = threadIdx.x >> 6;
  if (lane==0){ ssum[wv]=ls; ssq[wv]=lss; }
  __syncthreads();
  if (threadIdx.x==0){
    part[2*blockIdx.x]   = (double)(ssum[0]+ssum[1]+ssum[2]+ssum[3]);
    part[2*blockIdx.x+1] = (double)(ssq[0]+ssq[1]+ssq[2]+ssq[3]);
  }
}

// ---- reduce per-block partials -> red[0..1] (single block) ----
__global__ __launch_bounds__(256) void k_reduce(const double* __restrict__ part,
                                                int nblocks, double* __restrict__ red){
  int tid = threadIdx.x;
  double s = 0.0, q = 0.0;
  for (int i = tid; i < nblocks; i += 256){
    s += part[2*i];
    q += part[2*i+1];
  }
  __shared__ double shs[256], shq[256];
  shs[tid] = s; shq[tid] = q; __syncthreads();
  for (int o=128;o;o>>=1){
    if (tid<o){ shs[tid]+=shs[tid+o]; shq[tid]+=shq[tid+o]; }
    __syncthreads();
  }
  if (tid==0){ red[0]=shs[0]; red[1]=shq[0]; }
}

// -------- LayerNorm(graph) + ReLU + dropout (partitionable threefry, XOR-fold — VERIFIED R10) --------
__global__ __launch_bounds__(256) void ln_relu_drop(const unsigned short* __restrict__ v,
    unsigned short* __restrict__ h, const double* __restrict__ red,
    const float* __restrict__ gammaf, const float* __restrict__ betaf,
    uint32_t k0, uint32_t k1, int total, double tot)
{
  int j = blockIdx.x*256 + threadIdx.x;
  if (j >= total) return;
  double S = red[0], Q = red[1];
  double mu_d = S / tot;
  double var_d = Q / tot - mu_d*mu_d;
  if (var_d < 0.0) var_d = 0.0;
  float mu  = (float)mu_d;
  float inv = 1.0f / ((float)sqrt(var_d) + 1e-5f);

  uint32_t b0, b1;
  tf2x32(k0, k1, 0u, (uint32_t)j, &b0, &b1);   // counter hi=0, lo=j
  uint32_t bits = b0 ^ b1;                     // xor-fold (verified)
  float u = __uint_as_float((bits >> 9) | 0x3f800000u) - 1.0f;

  int c = j & (H_DIM-1);
  float y = fmaf((bfu(v[j]) - mu)*inv, gammaf[c], betaf[c]);
  y = fmaxf(y, 0.f);
  h[j] = f2bf((u < 0.8f) ? (y / 0.8f) : 0.f);
}

// ---------------- out = softmax(h @ W_out + b_out) -> f32 ----------------
__global__ __launch_bounds__(256) void out_softmax(const unsigned short* __restrict__ h,
    const float* __restrict__ Wo, const float* __restrict__ bo,
    float2* __restrict__ outv, int N)
{
  int node = (int)((blockIdx.x*256u + threadIdx.x) >> 6);
  int lane = threadIdx.x & 63;
  if (node >= N) return;
  unsigned int hv = ((const unsigned int*)(h + (size_t)node*H_DIM))[lane];
  float h0 = __uint_as_float(hv<<16), h1 = __uint_as_float(hv & 0xffff0000u);
  float4 wq = ((const float4*)Wo)[lane];
  float d0 = h0*wq.x + h1*wq.z;
  float d1 = h0*wq.y + h1*wq.w;
  for (int off=32; off; off>>=1){ d0 += __shfl_down(d0, off); d1 += __shfl_down(d1, off); }
  if (lane==0){
    d0 += bo[0]; d1 += bo[1];
    float m = fmaxf(d0, d1);
    float e0 = expf(d0 - m), e1 = expf(d1 - m);
    float s = e0 + e1;
    outv[node] = make_float2(e0/s, e1/s);
  }
}

// ---------------- launch ----------------
extern "C" void kernel_launch(void* const* d_in, const int* in_sizes, int n_in,
                              void* d_out, int out_size, void* d_ws, size_t ws_size,
                              hipStream_t stream) {
  (void)n_in; (void)out_size; (void)ws_size;
  const int N = in_sizes[0] / D_IN;     // x is [N, 64]
  const int E = in_sizes[1] / 2;        // edge_index is [2, E]
  const int total = N * H_DIM;
  const double tot = (double)total;

  const int* ei  = (const int*)d_in[1];
  const int* src = ei;
  const int* dst = ei + E;
  char* ws = (char*)d_ws;

  const int nb = (N + 1023) >> 10;      // scan blocks
  const int nodeBlocks = (N + 3) / 4;   // 64 lanes per node

  // runtime workspace layout, 256B-aligned slabs
  size_t o = 0;
  auto take = [&](size_t bytes)->char*{ char* p = ws + o; o = (o + bytes + 255) & ~(size_t)255; return p; };
  int*    flags  = (int*)   take(4*sizeof(int));   // [x, W_in, Wc, W_out]
  double* red    = (double*)take(4*sizeof(double));
  double* part   = (double*)take((size_t)nodeBlocks*2*sizeof(double));
  float*  dinv   = (float*) take((size_t)N*4);
  int*    cnt    = (int*)   take((size_t)N*4);
  int*    cur    = (int*)   take((size_t)N*4);
  int*    rowptr = (int*)   take(((size_t)N+1)*4);
  int*    bsum   = (int*)   take((size_t)nb*4);
  int*    boff   = (int*)   take((size_t)nb*4);
  float*  wc     = (float*) take((size_t)WC_TOT*4);
  int*    csr    = (int*)   take((size_t)E*4);
  unsigned short* actA = (unsigned short*)take((size_t)total*2);
  unsigned short* actB = (unsigned short*)take((size_t)total*2);

  // fold_in(key(1), i) = tf2x32(key=(0,1), counter=[0,i]) — verified
  uint32_t k00,k01,k10,k11;
  tf2x32(0u,1u,0u,0u,&k00,&k01);
  tf2x32(0u,1u,0u,1u,&k10,&k11);

  int pl0 = in_sizes[0] < 4096 ? in_sizes[0] : 4096;
  int pl1 = in_sizes[2] < 4096 ? in_sizes[2] : 4096;
  int pl2 = in_sizes[4] < 4096 ? in_sizes[4] : 4096;
  int pl3 = in_sizes[8] < 4096 ? in_sizes[8] : 4096;
  k_detect<<<1,256,0,stream>>>((const unsigned short*)d_in[0], pl0, flags+0);
  k_detect<<<1,256,0,stream>>>((const unsigned short*)d_in[2], pl1, flags+1);
  k_detect<<<1,256,0,stream>>>((const unsigned short*)d_in[4], pl2, flags+2);
  k_detect<<<1,256,0,stream>>>((const unsigned short*)d_in[8], pl3, flags+3);

  k_zero  <<<(N+255)/256, 256,0,stream>>>(cnt, cur, N);
  k_wconv <<<165, 256,0,stream>>>(d_in[2], d_in[3], d_in[4], d_in[5],
                                  d_in[6], d_in[7], d_in[8], d_in[9], wc, flags);
  k_count <<<(E+255)/256,256,0,stream>>>(dst, cnt, E);
  k_scan1 <<<nb,  256,0,stream>>>(cnt, bsum, N);
  k_scan2 <<<1,    64,0,stream>>>(bsum, boff, nb, rowptr, N);
  k_scan3 <<<nb,  256,0,stream>>>(cnt, boff, rowptr, dinv, N);
  k_fill  <<<(E+255)/256,256,0,stream>>>(src, dst, rowptr, cur, csr, E);

  const int gemmBlocks = (N + 63) / 64;
  const int fullBlocks = (total + 255) / 256;

  // A <- relu(x @ W_in + b_in)
  gemm_any<64,true,true><<<gemmBlocks,256,0,stream>>>(d_in[0], wc+WC_WIN, wc+WC_BIN, actA, N, flags+0);

  // layer 0
  gemm_any<128,false,false><<<gemmBlocks,256,0,stream>>>(actA, wc+WC_WC, wc+WC_BIN, actB, N, flags+0);
  gcn_gather<<<nodeBlocks,256,0,stream>>>(actB, rowptr, csr, dinv, wc+WC_BC, actA, part, N);
  k_reduce<<<1,256,0,stream>>>(part, nodeBlocks, red);
  ln_relu_drop<<<fullBlocks,256,0,stream>>>(actA, actB, red, wc+WC_G, wc+WC_B, k00, k01, total, tot);

  // layer 1
  gemm_any<128,false,false><<<gemmBlocks,256,0,stream>>>(actB, wc+WC_WC+16384, wc+WC_BIN, actA, N, flags+0);
  gcn_gather<<<nodeBlocks,256,0,stream>>>(actA, rowptr, csr, dinv, wc+WC_BC+128, actB, part, N);
  k_reduce<<<1,256,0,stream>>>(part, nodeBlocks, red+2);
  ln_relu_drop<<<fullBlocks,256,0,stream>>>(actB, actA, red+2, wc+WC_G+128, wc+WC_B+128, k10, k11, total, tot);

  // out (f32)
  out_softmax<<<nodeBlocks,256,0,stream>>>(actA, wc+WC_WO, wc+WC_BO, (float2*)d_out, N);
}

// Round 13
// 678.576 us; speedup vs baseline: 2.6153x; 1.0997x over previous
//
#include <hip/hip_runtime.h>
#include <stdint.h>

#define H_DIM 128   // hidden width (fixed by weight shapes)
#define D_IN  64    // input feature dim (fixed by weight shapes)

// ---------------- threefry2x32-20, bit-exact with JAX ----------------
__host__ __device__ __forceinline__ void tf2x32(uint32_t k0, uint32_t k1,
    uint32_t x0, uint32_t x1, uint32_t* o0, uint32_t* o1)
{
  uint32_t ks0 = k0, ks1 = k1, ks2 = k0 ^ k1 ^ 0x1BD11BDAu;
  x0 += ks0; x1 += ks1;
#define TFR(r) { x0 += x1; x1 = (x1 << (r)) | (x1 >> (32-(r))); x1 ^= x0; }
  TFR(13) TFR(15) TFR(26) TFR(6)   x0 += ks1; x1 += ks2 + 1u;
  TFR(17) TFR(29) TFR(16) TFR(24)  x0 += ks2; x1 += ks0 + 2u;
  TFR(13) TFR(15) TFR(26) TFR(6)   x0 += ks0; x1 += ks1 + 3u;
  TFR(17) TFR(29) TFR(16) TFR(24)  x0 += ks1; x1 += ks2 + 4u;
  TFR(13) TFR(15) TFR(26) TFR(6)   x0 += ks2; x1 += ks0 + 5u;
#undef TFR
  *o0 = x0; *o1 = x1;
}

__device__ __forceinline__ float bfu(unsigned short u){
  return __uint_as_float(((unsigned int)u) << 16);
}
__device__ __forceinline__ unsigned short f2bf(float f){  // RNE
  unsigned int u = __float_as_uint(f);
  u += 0x7fffu + ((u >> 16) & 1u);
  return (unsigned short)(u >> 16);
}

// canonical weight layout (float offsets) — architecture-fixed
#define WC_WIN 0
#define WC_BIN 8192
#define WC_WC  8320      // + layer*16384
#define WC_BC  41088     // + layer*128
#define WC_G   41344     // + layer*128
#define WC_B   41600     // + layer*128
#define WC_WO  41856
#define WC_BO  42112
#define WC_TOT 42114

// ---------------- per-buffer dtype detector (all groups f32 on this dataset; kept) ----------------
__global__ __launch_bounds__(256) void k_detect(const unsigned short* __restrict__ p,
                                                int limit, int* __restrict__ flag){
  int tid = threadIdx.x;
  int bad = 0;
  for (int i=0;i<16;++i){
    int idx = tid*16 + i;
    if (idx < limit){
      float f = bfu(p[idx]);
      if (!(fabsf(f) < 64.0f)) bad = 1;
    }
  }
  for (int off=32; off; off>>=1) bad |= __shfl_down(bad, off);
  __shared__ int sh[4];
  if ((tid&63)==0) sh[tid>>6] = bad;
  __syncthreads();
  if (tid==0) flag[0] = (sh[0]|sh[1]|sh[2]|sh[3]) ? 0 : 1;
}

// ---------------- init ----------------
__global__ __launch_bounds__(256) void k_zero(int* __restrict__ cnt, int N){
  int i = blockIdx.x*256 + threadIdx.x;
  if (i < N) cnt[i] = 0;
}

// ---------------- canonicalize weights to f32 (per-group dtype flags) ----------------
__global__ __launch_bounds__(256) void k_wconv(
    const void* __restrict__ W_in, const void* __restrict__ b_in,
    const void* __restrict__ Wc,  const void* __restrict__ bc,
    const void* __restrict__ gam, const void* __restrict__ bet,
    const void* __restrict__ W_o, const void* __restrict__ b_o,
    float* __restrict__ wc, const int* __restrict__ flags)
{
  int idx = blockIdx.x*256 + threadIdx.x;
  if (idx >= WC_TOT) return;
  const void* src; int li; int fsel;
  if      (idx < 8192)  { src=W_in; li=idx;       fsel=1; }
  else if (idx < 8320)  { src=b_in; li=idx-8192;  fsel=1; }
  else if (idx < 41088) { src=Wc;   li=idx-8320;  fsel=2; }
  else if (idx < 41344) { src=bc;   li=idx-41088; fsel=2; }
  else if (idx < 41600) { src=gam;  li=idx-41344; fsel=2; }
  else if (idx < 41856) { src=bet;  li=idx-41600; fsel=2; }
  else if (idx < 42112) { src=W_o;  li=idx-41856; fsel=3; }
  else                  { src=b_o;  li=idx-42112; fsel=3; }
  bool isbf = (flags[fsel] != 0);
  wc[idx] = isbf ? bfu(((const unsigned short*)src)[li]) : ((const float*)src)[li];
}

// ---------------- CSR build ----------------
// R13: k_count also records each edge's within-destination ordinal (perm),
// so k_fill needs NO atomics (and loses ~100MB of atomic-RMW writeback).
__global__ __launch_bounds__(256) void k_count(const int* __restrict__ dst, int* __restrict__ cnt,
                                               int* __restrict__ perm, int E){
  int e = blockIdx.x*256 + threadIdx.x;
  if (e < E){
    int p = atomicAdd(&cnt[dst[e]], 1);
    perm[e] = p;
  }
}
__global__ __launch_bounds__(256) void k_scan1(const int* __restrict__ cnt, int* __restrict__ bsum, int N){
  int tid = threadIdx.x;
  int base = blockIdx.x*1024 + tid*4;
  int s = 0;
  #pragma unroll
  for (int j=0;j<4;++j){ int idx = base+j; if (idx < N) s += cnt[idx]; }
  __shared__ int sh[256];
  sh[tid] = s; __syncthreads();
  for (int o=128;o;o>>=1){ if (tid<o) sh[tid]+=sh[tid+o]; __syncthreads(); }
  if (tid==0) bsum[blockIdx.x] = sh[0];
}
__global__ __launch_bounds__(64) void k_scan2(const int* __restrict__ bsum, int* __restrict__ boff,
                                              int nb, int* __restrict__ rowptr, int N){
  if (threadIdx.x==0 && blockIdx.x==0){
    int run = 0;
    for (int b=0;b<nb;++b){ boff[b]=run; run += bsum[b]; }
    rowptr[N] = run;   // == E
  }
}
__global__ __launch_bounds__(256) void k_scan3(const int* __restrict__ cnt, const int* __restrict__ boff,
                                               int* __restrict__ rowptr, float* __restrict__ dinv, int N){
  int tid = threadIdx.x;
  int base = blockIdx.x*1024 + tid*4;
  int a[4]; int tsum = 0;
  #pragma unroll
  for (int j=0;j<4;++j){ int idx=base+j; a[j] = (idx < N) ? cnt[idx] : 0; tsum += a[j]; }
  __shared__ int sh[256];
  sh[tid] = tsum; __syncthreads();
  for (int off=1; off<256; off<<=1){
    int v = 0; if (tid>=off) v = sh[tid-off];
    __syncthreads(); sh[tid] += v; __syncthreads();
  }
  int run = boff[blockIdx.x] + (sh[tid] - tsum);
  #pragma unroll
  for (int j=0;j<4;++j){
    int idx=base+j;
    if (idx < N){
      rowptr[idx] = run;
      dinv[idx] = 1.0f / sqrtf(1.0f + (float)a[j]);
    }
    run += a[j];
  }
}
__global__ __launch_bounds__(256) void k_fill(const int* __restrict__ src, const int* __restrict__ dst,
                                              const int* __restrict__ rowptr, const int* __restrict__ perm,
                                              int* __restrict__ csr, int E){
  int e = blockIdx.x*256 + threadIdx.x;
  if (e < E){
    int d = dst[e];
    csr[rowptr[d] + perm[e]] = src[e];   // atomic-free scatter
  }
}

// ------- GEMM: C[M,128] = A[M,K] @ B[K,128]; A ext (flag dtype) or internal bf16;
//         B canonical f32; C internal bf16; f32 accumulate -------
template<int K, bool EXT, bool RELUBIAS>
__global__ __launch_bounds__(256) void gemm_any(const void* __restrict__ Av,
    const float* __restrict__ Bw, const float* __restrict__ bias,
    unsigned short* __restrict__ C, int M, const int* __restrict__ flagp)
{
  __shared__ float As[64*K];
  const int tid = threadIdx.x;
  const int rowBase = blockIdx.x * 64;
  bool isbf = true;
  if (EXT) isbf = (*flagp != 0);
  #pragma unroll
  for (int it = 0; it < K/16; ++it) {
    int f = tid + it*256;                 // 4-elem group index
    int row = f / (K/4);
    int col = (f - row*(K/4))*4;
    int r = rowBase + row;
    float v0=0.f,v1=0.f,v2=0.f,v3=0.f;
    if (r < M) {
      if (!EXT || isbf) {
        const unsigned int* p = (const unsigned int*)((const unsigned short*)Av + (size_t)r*K + col);
        unsigned int a = p[0], b2 = p[1];
        v0 = __uint_as_float(a<<16);  v1 = __uint_as_float(a & 0xffff0000u);
        v2 = __uint_as_float(b2<<16); v3 = __uint_as_float(b2 & 0xffff0000u);
      } else {
        const float4 q = *(const float4*)((const float*)Av + (size_t)r*K + col);
        v0=q.x; v1=q.y; v2=q.z; v3=q.w;
      }
    }
    As[row*K+col]=v0; As[row*K+col+1]=v1; As[row*K+col+2]=v2; As[row*K+col+3]=v3;
  }
  __syncthreads();
  const int tx = tid & 31, ty = tid >> 5;
  const int c0 = tx*4;
  float acc[8][4];
  #pragma unroll
  for (int i=0;i<8;++i){ acc[i][0]=0.f; acc[i][1]=0.f; acc[i][2]=0.f; acc[i][3]=0.f; }
  #pragma unroll 4
  for (int k = 0; k < K; ++k) {
    float4 bq = *(const float4*)(Bw + (size_t)k*128 + c0);
    #pragma unroll
    for (int i=0;i<8;++i){
      float a = As[(ty*8+i)*K + k];
      acc[i][0] = fmaf(a,bq.x,acc[i][0]);
      acc[i][1] = fmaf(a,bq.y,acc[i][1]);
      acc[i][2] = fmaf(a,bq.z,acc[i][2]);
      acc[i][3] = fmaf(a,bq.w,acc[i][3]);
    }
  }
  float bb0=0.f,bb1=0.f,bb2=0.f,bb3=0.f;
  if (RELUBIAS){ bb0=bias[c0]; bb1=bias[c0+1]; bb2=bias[c0+2]; bb3=bias[c0+3]; }
  #pragma unroll
  for (int i=0;i<8;++i){
    int r = rowBase + ty*8 + i;
    if (r < M){
      float o0=acc[i][0], o1=acc[i][1], o2=acc[i][2], o3=acc[i][3];
      if (RELUBIAS){
        o0=fmaxf(o0+bb0,0.f); o1=fmaxf(o1+bb1,0.f);
        o2=fmaxf(o2+bb2,0.f); o3=fmaxf(o3+bb3,0.f);
      }
      uint2 pk;
      pk.x = (unsigned int)f2bf(o0) | ((unsigned int)f2bf(o1) << 16);
      pk.y = (unsigned int)f2bf(o2) | ((unsigned int)f2bf(o3) << 16);
      *(uint2*)(C + (size_t)r*128 + c0) = pk;
    }
  }
}

// ---- gather (no global atomics; per-block partials to `part`) ----
__global__ __launch_bounds__(256) void gcn_gather(const unsigned short* __restrict__ t,
    const int* __restrict__ rowptr, const int* __restrict__ csr,
    const float* __restrict__ dinv, const float* __restrict__ bcw,
    unsigned short* __restrict__ v, double* __restrict__ part, int N)
{
  int node = (int)((blockIdx.x*256u + threadIdx.x) >> 6);
  int lane = threadIdx.x & 63;
  float ls = 0.f, lss = 0.f;
  if (node < N){
    float dn = dinv[node];
    unsigned int tv = ((const unsigned int*)(t + (size_t)node*H_DIM))[lane];
    float ax = __uint_as_float(tv<<16), ay = __uint_as_float(tv & 0xffff0000u);
    float dn2 = dn*dn;
    ax *= dn2; ay *= dn2;
    int e0 = rowptr[node], e1 = rowptr[node+1];
    int e = e0;
    for (; e + 8 <= e1; e += 8){
      int s[8];
      #pragma unroll
      for (int q=0;q<8;++q) s[q] = csr[e+q];
      float cf[8];
      #pragma unroll
      for (int q=0;q<8;++q) cf[q] = dinv[s[q]];
      unsigned int rv[8];
      #pragma unroll
      for (int q=0;q<8;++q) rv[q] = ((const unsigned int*)(t + (size_t)s[q]*H_DIM))[lane];
      #pragma unroll
      for (int q=0;q<8;++q){
        float c = cf[q]*dn;
        ax = fmaf(__uint_as_float(rv[q]<<16),           c, ax);
        ay = fmaf(__uint_as_float(rv[q] & 0xffff0000u), c, ay);
      }
    }
    for (; e < e1; ++e){
      int s = csr[e];
      float c = dinv[s]*dn;
      unsigned int sv = ((const unsigned int*)(t + (size_t)s*H_DIM))[lane];
      ax = fmaf(__uint_as_float(sv<<16),           c, ax);
      ay = fmaf(__uint_as_float(sv & 0xffff0000u), c, ay);
    }
    ax += bcw[2*lane]; ay += bcw[2*lane+1];
    unsigned int pk = (unsigned int)f2bf(ax) | ((unsigned int)f2bf(ay) << 16);
    ((unsigned int*)(v + (size_t)node*H_DIM))[lane] = pk;
    ls  = ax + ay;
    lss = ax*ax + ay*ay;
  }
  for (int off=32; off; off>>=1){ ls += __shfl_down(ls, off); lss += __shfl_down(lss, off); }
  __shared__ float ssum[4], ssq[4];
  int wv = threadIdx.x >> 6;
  if (lane==0){ ssum[wv]=ls; ssq[wv]=lss; }
  __syncthreads();
  if (threadIdx.x==0){
    part[2*blockIdx.x]   = (double)(ssum[0]+ssum[1]+ssum[2]+ssum[3]);
    part[2*blockIdx.x+1] = (double)(ssq[0]+ssq[1]+ssq[2]+ssq[3]);
  }
}

// ---- reduce per-block partials -> red[0..1] (single block) ----
__global__ __launch_bounds__(256) void k_reduce(const double* __restrict__ part,
                                                int nblocks, double* __restrict__ red){
  int tid = threadIdx.x;
  double s = 0.0, q = 0.0;
  for (int i = tid; i < nblocks; i += 256){
    s += part[2*i];
    q += part[2*i+1];
  }
  __shared__ double shs[256], shq[256];
  shs[tid] = s; shq[tid] = q; __syncthreads();
  for (int o=128;o;o>>=1){
    if (tid<o){ shs[tid]+=shs[tid+o]; shq[tid]+=shq[tid+o]; }
    __syncthreads();
  }
  if (tid==0){ red[0]=shs[0]; red[1]=shq[0]; }
}

// -------- LayerNorm(graph) + ReLU + dropout (partitionable threefry, XOR-fold — VERIFIED R10) --------
__global__ __launch_bounds__(256) void ln_relu_drop(const unsigned short* __restrict__ v,
    unsigned short* __restrict__ h, const double* __restrict__ red,
    const float* __restrict__ gammaf, const float* __restrict__ betaf,
    uint32_t k0, uint32_t k1, int total, double tot)
{
  int j = blockIdx.x*256 + threadIdx.x;
  if (j >= total) return;
  double S = red[0], Q = red[1];
  double mu_d = S / tot;
  double var_d = Q / tot - mu_d*mu_d;
  if (var_d < 0.0) var_d = 0.0;
  float mu  = (float)mu_d;
  float inv = 1.0f / ((float)sqrt(var_d) + 1e-5f);

  uint32_t b0, b1;
  tf2x32(k0, k1, 0u, (uint32_t)j, &b0, &b1);   // counter hi=0, lo=j
  uint32_t bits = b0 ^ b1;                     // xor-fold (verified)
  float u = __uint_as_float((bits >> 9) | 0x3f800000u) - 1.0f;

  int c = j & (H_DIM-1);
  float y = fmaf((bfu(v[j]) - mu)*inv, gammaf[c], betaf[c]);
  y = fmaxf(y, 0.f);
  h[j] = f2bf((u < 0.8f) ? (y / 0.8f) : 0.f);
}

// ---------------- out = softmax(h @ W_out + b_out) -> f32 ----------------
__global__ __launch_bounds__(256) void out_softmax(const unsigned short* __restrict__ h,
    const float* __restrict__ Wo, const float* __restrict__ bo,
    float2* __restrict__ outv, int N)
{
  int node = (int)((blockIdx.x*256u + threadIdx.x) >> 6);
  int lane = threadIdx.x & 63;
  if (node >= N) return;
  unsigned int hv = ((const unsigned int*)(h + (size_t)node*H_DIM))[lane];
  float h0 = __uint_as_float(hv<<16), h1 = __uint_as_float(hv & 0xffff0000u);
  float4 wq = ((const float4*)Wo)[lane];
  float d0 = h0*wq.x + h1*wq.z;
  float d1 = h0*wq.y + h1*wq.w;
  for (int off=32; off; off>>=1){ d0 += __shfl_down(d0, off); d1 += __shfl_down(d1, off); }
  if (lane==0){
    d0 += bo[0]; d1 += bo[1];
    float m = fmaxf(d0, d1);
    float e0 = expf(d0 - m), e1 = expf(d1 - m);
    float s = e0 + e1;
    outv[node] = make_float2(e0/s, e1/s);
  }
}

// ---------------- launch ----------------
extern "C" void kernel_launch(void* const* d_in, const int* in_sizes, int n_in,
                              void* d_out, int out_size, void* d_ws, size_t ws_size,
                              hipStream_t stream) {
  (void)n_in; (void)out_size; (void)ws_size;
  const int N = in_sizes[0] / D_IN;     // x is [N, 64]
  const int E = in_sizes[1] / 2;        // edge_index is [2, E]
  const int total = N * H_DIM;
  const double tot = (double)total;

  const int* ei  = (const int*)d_in[1];
  const int* src = ei;
  const int* dst = ei + E;
  char* ws = (char*)d_ws;

  const int nb = (N + 1023) >> 10;      // scan blocks
  const int nodeBlocks = (N + 3) / 4;   // 64 lanes per node

  // runtime workspace layout, 256B-aligned slabs
  size_t o = 0;
  auto take = [&](size_t bytes)->char*{ char* p = ws + o; o = (o + bytes + 255) & ~(size_t)255; return p; };
  int*    flags  = (int*)   take(4*sizeof(int));   // [x, W_in, Wc, W_out]
  double* red    = (double*)take(4*sizeof(double));
  double* part   = (double*)take((size_t)nodeBlocks*2*sizeof(double));
  float*  dinv   = (float*) take((size_t)N*4);
  int*    cnt    = (int*)   take((size_t)N*4);
  int*    rowptr = (int*)   take(((size_t)N+1)*4);
  int*    bsum   = (int*)   take((size_t)nb*4);
  int*    boff   = (int*)   take((size_t)nb*4);
  float*  wc     = (float*) take((size_t)WC_TOT*4);
  int*    csr    = (int*)   take((size_t)E*4);
  int*    perm   = (int*)   take((size_t)E*4);
  unsigned short* actA = (unsigned short*)take((size_t)total*2);
  unsigned short* actB = (unsigned short*)take((size_t)total*2);

  // fold_in(key(1), i) = tf2x32(key=(0,1), counter=[0,i]) — verified
  uint32_t k00,k01,k10,k11;
  tf2x32(0u,1u,0u,0u,&k00,&k01);
  tf2x32(0u,1u,0u,1u,&k10,&k11);

  int pl0 = in_sizes[0] < 4096 ? in_sizes[0] : 4096;
  int pl1 = in_sizes[2] < 4096 ? in_sizes[2] : 4096;
  int pl2 = in_sizes[4] < 4096 ? in_sizes[4] : 4096;
  int pl3 = in_sizes[8] < 4096 ? in_sizes[8] : 4096;
  k_detect<<<1,256,0,stream>>>((const unsigned short*)d_in[0], pl0, flags+0);
  k_detect<<<1,256,0,stream>>>((const unsigned short*)d_in[2], pl1, flags+1);
  k_detect<<<1,256,0,stream>>>((const unsigned short*)d_in[4], pl2, flags+2);
  k_detect<<<1,256,0,stream>>>((const unsigned short*)d_in[8], pl3, flags+3);

  k_zero  <<<(N+255)/256, 256,0,stream>>>(cnt, N);
  k_wconv <<<165, 256,0,stream>>>(d_in[2], d_in[3], d_in[4], d_in[5],
                                  d_in[6], d_in[7], d_in[8], d_in[9], wc, flags);
  k_count <<<(E+255)/256,256,0,stream>>>(dst, cnt, perm, E);
  k_scan1 <<<nb,  256,0,stream>>>(cnt, bsum, N);
  k_scan2 <<<1,    64,0,stream>>>(bsum, boff, nb, rowptr, N);
  k_scan3 <<<nb,  256,0,stream>>>(cnt, boff, rowptr, dinv, N);
  k_fill  <<<(E+255)/256,256,0,stream>>>(src, dst, rowptr, perm, csr, E);

  const int gemmBlocks = (N + 63) / 64;
  const int fullBlocks = (total + 255) / 256;

  // A <- relu(x @ W_in + b_in)
  gemm_any<64,true,true><<<gemmBlocks,256,0,stream>>>(d_in[0], wc+WC_WIN, wc+WC_BIN, actA, N, flags+0);

  // layer 0
  gemm_any<128,false,false><<<gemmBlocks,256,0,stream>>>(actA, wc+WC_WC, wc+WC_BIN, actB, N, flags+0);
  gcn_gather<<<nodeBlocks,256,0,stream>>>(actB, rowptr, csr, dinv, wc+WC_BC, actA, part, N);
  k_reduce<<<1,256,0,stream>>>(part, nodeBlocks, red);
  ln_relu_drop<<<fullBlocks,256,0,stream>>>(actA, actB, red, wc+WC_G, wc+WC_B, k00, k01, total, tot);

  // layer 1
  gemm_any<128,false,false><<<gemmBlocks,256,0,stream>>>(actB, wc+WC_WC+16384, wc+WC_BIN, actA, N, flags+0);
  gcn_gather<<<nodeBlocks,256,0,stream>>>(actA, rowptr, csr, dinv, wc+WC_BC+128, actB, part, N);
  k_reduce<<<1,256,0,stream>>>(part, nodeBlocks, red+2);
  ln_relu_drop<<<fullBlocks,256,0,stream>>>(actB, actA, red+2, wc+WC_G+128, wc+WC_B+128, k10, k11, total, tot);

  // out (f32)
  out_softmax<<<nodeBlocks,256,0,stream>>>(actA, wc+WC_WO, wc+WC_BO, (float2*)d_out, N);
}

// Round 14
// 636.981 us; speedup vs baseline: 2.7861x; 1.0653x over previous
//
#include <hip/hip_runtime.h>
#include <stdint.h>

#define H_DIM 128   // hidden width (fixed by weight shapes)
#define D_IN  64    // input feature dim (fixed by weight shapes)

typedef __attribute__((ext_vector_type(8))) short bf16x8;
typedef __attribute__((ext_vector_type(4))) float f32x4;

// ---------------- threefry2x32-20, bit-exact with JAX ----------------
__host__ __device__ __forceinline__ void tf2x32(uint32_t k0, uint32_t k1,
    uint32_t x0, uint32_t x1, uint32_t* o0, uint32_t* o1)
{
  uint32_t ks0 = k0, ks1 = k1, ks2 = k0 ^ k1 ^ 0x1BD11BDAu;
  x0 += ks0; x1 += ks1;
#define TFR(r) { x0 += x1; x1 = (x1 << (r)) | (x1 >> (32-(r))); x1 ^= x0; }
  TFR(13) TFR(15) TFR(26) TFR(6)   x0 += ks1; x1 += ks2 + 1u;
  TFR(17) TFR(29) TFR(16) TFR(24)  x0 += ks2; x1 += ks0 + 2u;
  TFR(13) TFR(15) TFR(26) TFR(6)   x0 += ks0; x1 += ks1 + 3u;
  TFR(17) TFR(29) TFR(16) TFR(24)  x0 += ks1; x1 += ks2 + 4u;
  TFR(13) TFR(15) TFR(26) TFR(6)   x0 += ks2; x1 += ks0 + 5u;
#undef TFR
  *o0 = x0; *o1 = x1;
}

__device__ __forceinline__ float bfu(unsigned short u){
  return __uint_as_float(((unsigned int)u) << 16);
}
__device__ __forceinline__ unsigned short f2bf(float f){  // RNE
  unsigned int u = __float_as_uint(f);
  u += 0x7fffu + ((u >> 16) & 1u);
  return (unsigned short)(u >> 16);
}

// canonical weight layout (float offsets) — architecture-fixed
#define WC_WIN 0
#define WC_BIN 8192
#define WC_WC  8320      // + layer*16384
#define WC_BC  41088     // + layer*128
#define WC_G   41344     // + layer*128
#define WC_B   41600     // + layer*128
#define WC_WO  41856
#define WC_BO  42112
#define WC_TOT 42114

// bf16 transposed weight layout (ushort offsets): WtIn[128][64], WtC0[128][128], WtC1[128][128]
#define WT_IN  0
#define WT_C0  8192
#define WT_C1  24576
#define WT_TOT 40960

// ---------------- per-buffer dtype detector (all groups f32 on this dataset; kept) ----------------
__global__ __launch_bounds__(256) void k_detect(const unsigned short* __restrict__ p,
                                                int limit, int* __restrict__ flag){
  int tid = threadIdx.x;
  int bad = 0;
  for (int i=0;i<16;++i){
    int idx = tid*16 + i;
    if (idx < limit){
      float f = bfu(p[idx]);
      if (!(fabsf(f) < 64.0f)) bad = 1;
    }
  }
  for (int off=32; off; off>>=1) bad |= __shfl_down(bad, off);
  __shared__ int sh[4];
  if ((tid&63)==0) sh[tid>>6] = bad;
  __syncthreads();
  if (tid==0) flag[0] = (sh[0]|sh[1]|sh[2]|sh[3]) ? 0 : 1;
}

// ---------------- init ----------------
__global__ __launch_bounds__(256) void k_zero(int* __restrict__ cnt, int N){
  int i = blockIdx.x*256 + threadIdx.x;
  if (i < N) cnt[i] = 0;
}

// ---------------- canonicalize weights to f32 (per-group dtype flags) ----------------
__global__ __launch_bounds__(256) void k_wconv(
    const void* __restrict__ W_in, const void* __restrict__ b_in,
    const void* __restrict__ Wc,  const void* __restrict__ bc,
    const void* __restrict__ gam, const void* __restrict__ bet,
    const void* __restrict__ W_o, const void* __restrict__ b_o,
    float* __restrict__ wc, const int* __restrict__ flags)
{
  int idx = blockIdx.x*256 + threadIdx.x;
  if (idx >= WC_TOT) return;
  const void* src; int li; int fsel;
  if      (idx < 8192)  { src=W_in; li=idx;       fsel=1; }
  else if (idx < 8320)  { src=b_in; li=idx-8192;  fsel=1; }
  else if (idx < 41088) { src=Wc;   li=idx-8320;  fsel=2; }
  else if (idx < 41344) { src=bc;   li=idx-41088; fsel=2; }
  else if (idx < 41600) { src=gam;  li=idx-41344; fsel=2; }
  else if (idx < 41856) { src=bet;  li=idx-41600; fsel=2; }
  else if (idx < 42112) { src=W_o;  li=idx-41856; fsel=3; }
  else                  { src=b_o;  li=idx-42112; fsel=3; }
  bool isbf = (flags[fsel] != 0);
  wc[idx] = isbf ? bfu(((const unsigned short*)src)[li]) : ((const float*)src)[li];
}

// ---- bf16 transposed weight copies for MFMA B-operands (run after k_wconv) ----
__global__ __launch_bounds__(256) void k_wtrans(const float* __restrict__ wc,
                                                unsigned short* __restrict__ wt){
  int idx = blockIdx.x*256 + threadIdx.x;
  if (idx >= WT_TOT) return;
  if (idx < WT_C0){                 // WtIn[n][k] = W_in[k][n], n<128, k<64
    int n = idx >> 6, k = idx & 63;
    wt[idx] = f2bf(wc[WC_WIN + k*128 + n]);
  } else if (idx < WT_C1){          // WtC0[n][k] = Wc0[k][n]
    int r = idx - WT_C0; int n = r >> 7, k = r & 127;
    wt[idx] = f2bf(wc[WC_WC + k*128 + n]);
  } else {                          // WtC1[n][k] = Wc1[k][n]
    int r = idx - WT_C1; int n = r >> 7, k = r & 127;
    wt[idx] = f2bf(wc[WC_WC + 16384 + k*128 + n]);
  }
}

// ---------------- CSR build ----------------
__global__ __launch_bounds__(256) void k_count(const int* __restrict__ dst, int* __restrict__ cnt,
                                               int* __restrict__ perm, int E){
  int e = blockIdx.x*256 + threadIdx.x;
  if (e < E){
    int p = atomicAdd(&cnt[dst[e]], 1);
    perm[e] = p;
  }
}
__global__ __launch_bounds__(256) void k_scan1(const int* __restrict__ cnt, int* __restrict__ bsum, int N){
  int tid = threadIdx.x;
  int base = blockIdx.x*1024 + tid*4;
  int s = 0;
  #pragma unroll
  for (int j=0;j<4;++j){ int idx = base+j; if (idx < N) s += cnt[idx]; }
  __shared__ int sh[256];
  sh[tid] = s; __syncthreads();
  for (int o=128;o;o>>=1){ if (tid<o) sh[tid]+=sh[tid+o]; __syncthreads(); }
  if (tid==0) bsum[blockIdx.x] = sh[0];
}
__global__ __launch_bounds__(64) void k_scan2(const int* __restrict__ bsum, int* __restrict__ boff,
                                              int nb, int* __restrict__ rowptr, int N){
  if (threadIdx.x==0 && blockIdx.x==0){
    int run = 0;
    for (int b=0;b<nb;++b){ boff[b]=run; run += bsum[b]; }
    rowptr[N] = run;   // == E
  }
}
__global__ __launch_bounds__(256) void k_scan3(const int* __restrict__ cnt, const int* __restrict__ boff,
                                               int* __restrict__ rowptr, float* __restrict__ dinv, int N){
  int tid = threadIdx.x;
  int base = blockIdx.x*1024 + tid*4;
  int a[4]; int tsum = 0;
  #pragma unroll
  for (int j=0;j<4;++j){ int idx=base+j; a[j] = (idx < N) ? cnt[idx] : 0; tsum += a[j]; }
  __shared__ int sh[256];
  sh[tid] = tsum; __syncthreads();
  for (int off=1; off<256; off<<=1){
    int v = 0; if (tid>=off) v = sh[tid-off];
    __syncthreads(); sh[tid] += v; __syncthreads();
  }
  int run = boff[blockIdx.x] + (sh[tid] - tsum);
  #pragma unroll
  for (int j=0;j<4;++j){
    int idx=base+j;
    if (idx < N){
      rowptr[idx] = run;
      dinv[idx] = 1.0f / sqrtf(1.0f + (float)a[j]);
    }
    run += a[j];
  }
}
__global__ __launch_bounds__(256) void k_fill(const int* __restrict__ src, const int* __restrict__ dst,
                                              const int* __restrict__ rowptr, const int* __restrict__ perm,
                                              int* __restrict__ csr, int E){
  int e = blockIdx.x*256 + threadIdx.x;
  if (e < E){
    int d = dst[e];
    csr[rowptr[d] + perm[e]] = src[e];   // atomic-free scatter
  }
}

// ------- MFMA GEMM (R14): C[M,128] = A[M,K] @ B[K,128], bf16 inputs, f32 accum.
// Bt is B transposed [128][K] bf16 so B-frags are contiguous 16B loads.
// Layouts (verified, learn_hip m89/m120): A-op A[m=lane&15][k=quad*8+j];
// B-op B[k=quad*8+j][n=lane&15]; C/D col=lane&15, row=quad*4+reg.
// Block: 64 rows x 128 cols, 4 waves; wave = 4 M-tiles x 2 N-tiles, K/32 steps.
template<int K, bool EXT, bool RELUBIAS>
__global__ __launch_bounds__(256) void gemm_mfma(const void* __restrict__ Av,
    const unsigned short* __restrict__ Bt, const float* __restrict__ bias,
    unsigned short* __restrict__ C, int M, const int* __restrict__ flagp)
{
  const int tid  = threadIdx.x;
  const int wid  = tid >> 6;
  const int lane = tid & 63;
  const int l15  = lane & 15;
  const int quad = lane >> 4;
  const int rowBase = blockIdx.x * 64;
  const int col0 = wid * 32;

  bool isbf = true;
  if (EXT) isbf = (*flagp != 0);

  f32x4 acc[4][2];
  #pragma unroll
  for (int mt=0;mt<4;++mt)
    #pragma unroll
    for (int nt=0;nt<2;++nt) acc[mt][nt] = (f32x4){0.f,0.f,0.f,0.f};

  #pragma unroll
  for (int k0 = 0; k0 < K; k0 += 32){
    bf16x8 bf[2];
    #pragma unroll
    for (int nt=0;nt<2;++nt)
      bf[nt] = *(const bf16x8*)(Bt + (size_t)(col0 + nt*16 + l15)*K + k0 + quad*8);
    #pragma unroll
    for (int mt=0;mt<4;++mt){
      int r = rowBase + mt*16 + l15;
      if (r >= M) r = M-1;             // clamped load; store is guarded
      bf16x8 af;
      if (!EXT || isbf){
        af = *(const bf16x8*)((const unsigned short*)Av + (size_t)r*K + k0 + quad*8);
      } else {
        const float* ap = (const float*)Av + (size_t)r*K + k0 + quad*8;
        #pragma unroll
        for (int j=0;j<8;++j) ((unsigned short*)&af)[j] = f2bf(ap[j]);
      }
      #pragma unroll
      for (int nt=0;nt<2;++nt)
        acc[mt][nt] = __builtin_amdgcn_mfma_f32_16x16x32_bf16(af, bf[nt], acc[mt][nt], 0,0,0);
    }
  }

  #pragma unroll
  for (int mt=0;mt<4;++mt){
    #pragma unroll
    for (int nt=0;nt<2;++nt){
      int col = col0 + nt*16 + l15;
      float bb = 0.f;
      if (RELUBIAS) bb = bias[col];
      #pragma unroll
      for (int reg=0;reg<4;++reg){
        int row = rowBase + mt*16 + quad*4 + reg;
        if (row < M){
          float vv = acc[mt][nt][reg];
          if (RELUBIAS) vv = fmaxf(vv + bb, 0.f);
          C[(size_t)row*128 + col] = f2bf(vv);
        }
      }
    }
  }
}

// ---- gather (no global atomics; per-block partials to `part`) ----
__global__ __launch_bounds__(256) void gcn_gather(const unsigned short* __restrict__ t,
    const int* __restrict__ rowptr, const int* __restrict__ csr,
    const float* __restrict__ dinv, const float* __restrict__ bcw,
    unsigned short* __restrict__ v, double* __restrict__ part, int N)
{
  int node = (int)((blockIdx.x*256u + threadIdx.x) >> 6);
  int lane = threadIdx.x & 63;
  float ls = 0.f, lss = 0.f;
  if (node < N){
    float dn = dinv[node];
    unsigned int tv = ((const unsigned int*)(t + (size_t)node*H_DIM))[lane];
    float ax = __uint_as_float(tv<<16), ay = __uint_as_float(tv & 0xffff0000u);
    float dn2 = dn*dn;
    ax *= dn2; ay *= dn2;
    int e0 = rowptr[node], e1 = rowptr[node+1];
    int e = e0;
    for (; e + 8 <= e1; e += 8){
      int s[8];
      #pragma unroll
      for (int q=0;q<8;++q) s[q] = csr[e+q];
      float cf[8];
      #pragma unroll
      for (int q=0;q<8;++q) cf[q] = dinv[s[q]];
      unsigned int rv[8];
      #pragma unroll
      for (int q=0;q<8;++q) rv[q] = ((const unsigned int*)(t + (size_t)s[q]*H_DIM))[lane];
      #pragma unroll
      for (int q=0;q<8;++q){
        float c = cf[q]*dn;
        ax = fmaf(__uint_as_float(rv[q]<<16),           c, ax);
        ay = fmaf(__uint_as_float(rv[q] & 0xffff0000u), c, ay);
      }
    }
    for (; e < e1; ++e){
      int s = csr[e];
      float c = dinv[s]*dn;
      unsigned int sv = ((const unsigned int*)(t + (size_t)s*H_DIM))[lane];
      ax = fmaf(__uint_as_float(sv<<16),           c, ax);
      ay = fmaf(__uint_as_float(sv & 0xffff0000u), c, ay);
    }
    ax += bcw[2*lane]; ay += bcw[2*lane+1];
    unsigned int pk = (unsigned int)f2bf(ax) | ((unsigned int)f2bf(ay) << 16);
    ((unsigned int*)(v + (size_t)node*H_DIM))[lane] = pk;
    ls  = ax + ay;
    lss = ax*ax + ay*ay;
  }
  for (int off=32; off; off>>=1){ ls += __shfl_down(ls, off); lss += __shfl_down(lss, off); }
  __shared__ float ssum[4], ssq[4];
  int wv = threadIdx.x >> 6;
  if (lane==0){ ssum[wv]=ls; ssq[wv]=lss; }
  __syncthreads();
  if (threadIdx.x==0){
    part[2*blockIdx.x]   = (double)(ssum[0]+ssum[1]+ssum[2]+ssum[3]);
    part[2*blockIdx.x+1] = (double)(ssq[0]+ssq[1]+ssq[2]+ssq[3]);
  }
}

// ---- reduce per-block partials -> red[0..1] (single block) ----
__global__ __launch_bounds__(256) void k_reduce(const double* __restrict__ part,
                                                int nblocks, double* __restrict__ red){
  int tid = threadIdx.x;
  double s = 0.0, q = 0.0;
  for (int i = tid; i < nblocks; i += 256){
    s += part[2*i];
    q += part[2*i+1];
  }
  __shared__ double shs[256], shq[256];
  shs[tid] = s; shq[tid] = q; __syncthreads();
  for (int o=128;o;o>>=1){
    if (tid<o){ shs[tid]+=shs[tid+o]; shq[tid]+=shq[tid+o]; }
    __syncthreads();
  }
  if (tid==0){ red[0]=shs[0]; red[1]=shq[0]; }
}

// -------- LayerNorm(graph) + ReLU + dropout (partitionable threefry, XOR-fold — VERIFIED R10) --------
__global__ __launch_bounds__(256) void ln_relu_drop(const unsigned short* __restrict__ v,
    unsigned short* __restrict__ h, const double* __restrict__ red,
    const float* __restrict__ gammaf, const float* __restrict__ betaf,
    uint32_t k0, uint32_t k1, int total, double tot)
{
  int j = blockIdx.x*256 + threadIdx.x;
  if (j >= total) return;
  double S = red[0], Q = red[1];
  double mu_d = S / tot;
  double var_d = Q / tot - mu_d*mu_d;
  if (var_d < 0.0) var_d = 0.0;
  float mu  = (float)mu_d;
  float inv = 1.0f / ((float)sqrt(var_d) + 1e-5f);

  uint32_t b0, b1;
  tf2x32(k0, k1, 0u, (uint32_t)j, &b0, &b1);   // counter hi=0, lo=j
  uint32_t bits = b0 ^ b1;                     // xor-fold (verified)
  float u = __uint_as_float((bits >> 9) | 0x3f800000u) - 1.0f;

  int c = j & (H_DIM-1);
  float y = fmaf((bfu(v[j]) - mu)*inv, gammaf[c], betaf[c]);
  y = fmaxf(y, 0.f);
  h[j] = f2bf((u < 0.8f) ? (y / 0.8f) : 0.f);
}

// ---------------- out = softmax(h @ W_out + b_out) -> f32 ----------------
__global__ __launch_bounds__(256) void out_softmax(const unsigned short* __restrict__ h,
    const float* __restrict__ Wo, const float* __restrict__ bo,
    float2* __restrict__ outv, int N)
{
  int node = (int)((blockIdx.x*256u + threadIdx.x) >> 6);
  int lane = threadIdx.x & 63;
  if (node >= N) return;
  unsigned int hv = ((const unsigned int*)(h + (size_t)node*H_DIM))[lane];
  float h0 = __uint_as_float(hv<<16), h1 = __uint_as_float(hv & 0xffff0000u);
  float4 wq = ((const float4*)Wo)[lane];
  float d0 = h0*wq.x + h1*wq.z;
  float d1 = h0*wq.y + h1*wq.w;
  for (int off=32; off; off>>=1){ d0 += __shfl_down(d0, off); d1 += __shfl_down(d1, off); }
  if (lane==0){
    d0 += bo[0]; d1 += bo[1];
    float m = fmaxf(d0, d1);
    float e0 = expf(d0 - m), e1 = expf(d1 - m);
    float s = e0 + e1;
    outv[node] = make_float2(e0/s, e1/s);
  }
}

// ---------------- launch ----------------
extern "C" void kernel_launch(void* const* d_in, const int* in_sizes, int n_in,
                              void* d_out, int out_size, void* d_ws, size_t ws_size,
                              hipStream_t stream) {
  (void)n_in; (void)out_size; (void)ws_size;
  const int N = in_sizes[0] / D_IN;     // x is [N, 64]
  const int E = in_sizes[1] / 2;        // edge_index is [2, E]
  const int total = N * H_DIM;
  const double tot = (double)total;

  const int* ei  = (const int*)d_in[1];
  const int* src = ei;
  const int* dst = ei + E;
  char* ws = (char*)d_ws;

  const int nb = (N + 1023) >> 10;      // scan blocks
  const int nodeBlocks = (N + 3) / 4;   // 64 lanes per node

  // runtime workspace layout, 256B-aligned slabs
  size_t o = 0;
  auto take = [&](size_t bytes)->char*{ char* p = ws + o; o = (o + bytes + 255) & ~(size_t)255; return p; };
  int*    flags  = (int*)   take(4*sizeof(int));   // [x, W_in, Wc, W_out]
  double* red    = (double*)take(4*sizeof(double));
  double* part   = (double*)take((size_t)nodeBlocks*2*sizeof(double));
  float*  dinv   = (float*) take((size_t)N*4);
  int*    cnt    = (int*)   take((size_t)N*4);
  int*    rowptr = (int*)   take(((size_t)N+1)*4);
  int*    bsum   = (int*)   take((size_t)nb*4);
  int*    boff   = (int*)   take((size_t)nb*4);
  float*  wc     = (float*) take((size_t)WC_TOT*4);
  unsigned short* wt = (unsigned short*)take((size_t)WT_TOT*2);
  int*    csr    = (int*)   take((size_t)E*4);
  int*    perm   = (int*)   take((size_t)E*4);
  unsigned short* actA = (unsigned short*)take((size_t)total*2);
  unsigned short* actB = (unsigned short*)take((size_t)total*2);

  // fold_in(key(1), i) = tf2x32(key=(0,1), counter=[0,i]) — verified
  uint32_t k00,k01,k10,k11;
  tf2x32(0u,1u,0u,0u,&k00,&k01);
  tf2x32(0u,1u,0u,1u,&k10,&k11);

  int pl0 = in_sizes[0] < 4096 ? in_sizes[0] : 4096;
  int pl1 = in_sizes[2] < 4096 ? in_sizes[2] : 4096;
  int pl2 = in_sizes[4] < 4096 ? in_sizes[4] : 4096;
  int pl3 = in_sizes[8] < 4096 ? in_sizes[8] : 4096;
  k_detect<<<1,256,0,stream>>>((const unsigned short*)d_in[0], pl0, flags+0);
  k_detect<<<1,256,0,stream>>>((const unsigned short*)d_in[2], pl1, flags+1);
  k_detect<<<1,256,0,stream>>>((const unsigned short*)d_in[4], pl2, flags+2);
  k_detect<<<1,256,0,stream>>>((const unsigned short*)d_in[8], pl3, flags+3);

  k_zero  <<<(N+255)/256, 256,0,stream>>>(cnt, N);
  k_wconv <<<165, 256,0,stream>>>(d_in[2], d_in[3], d_in[4], d_in[5],
                                  d_in[6], d_in[7], d_in[8], d_in[9], wc, flags);
  k_wtrans<<<160, 256,0,stream>>>(wc, wt);
  k_count <<<(E+255)/256,256,0,stream>>>(dst, cnt, perm, E);
  k_scan1 <<<nb,  256,0,stream>>>(cnt, bsum, N);
  k_scan2 <<<1,    64,0,stream>>>(bsum, boff, nb, rowptr, N);
  k_scan3 <<<nb,  256,0,stream>>>(cnt, boff, rowptr, dinv, N);
  k_fill  <<<(E+255)/256,256,0,stream>>>(src, dst, rowptr, perm, csr, E);

  const int gemmBlocks = (N + 63) / 64;
  const int fullBlocks = (total + 255) / 256;

  // A <- relu(x @ W_in + b_in)   [MFMA]
  gemm_mfma<64,true,true><<<gemmBlocks,256,0,stream>>>(d_in[0], wt+WT_IN, wc+WC_BIN, actA, N, flags+0);

  // layer 0
  gemm_mfma<128,false,false><<<gemmBlocks,256,0,stream>>>(actA, wt+WT_C0, wc+WC_BIN, actB, N, flags+0);
  gcn_gather<<<nodeBlocks,256,0,stream>>>(actB, rowptr, csr, dinv, wc+WC_BC, actA, part, N);
  k_reduce<<<1,256,0,stream>>>(part, nodeBlocks, red);
  ln_relu_drop<<<fullBlocks,256,0,stream>>>(actA, actB, red, wc+WC_G, wc+WC_B, k00, k01, total, tot);

  // layer 1
  gemm_mfma<128,false,false><<<gemmBlocks,256,0,stream>>>(actB, wt+WT_C1, wc+WC_BIN, actA, N, flags+0);
  gcn_gather<<<nodeBlocks,256,0,stream>>>(actA, rowptr, csr, dinv, wc+WC_BC+128, actB, part, N);
  k_reduce<<<1,256,0,stream>>>(part, nodeBlocks, red+2);
  ln_relu_drop<<<fullBlocks,256,0,stream>>>(actB, actA, red+2, wc+WC_G+128, wc+WC_B+128, k10, k11, total, tot);

  // out (f32)
  out_softmax<<<nodeBlocks,256,0,stream>>>(actA, wc+WC_WO, wc+WC_BO, (float2*)d_out, N);
}

// Round 15
// 622.961 us; speedup vs baseline: 2.8488x; 1.0225x over previous
//
#include <hip/hip_runtime.h>
#include <stdint.h>

#define H_DIM 128   // hidden width (fixed by weight shapes)
#define D_IN  64    // input feature dim (fixed by weight shapes)

typedef __attribute__((ext_vector_type(8))) short bf16x8;
typedef __attribute__((ext_vector_type(4))) float f32x4;

// ---------------- threefry2x32-20, bit-exact with JAX ----------------
__host__ __device__ __forceinline__ void tf2x32(uint32_t k0, uint32_t k1,
    uint32_t x0, uint32_t x1, uint32_t* o0, uint32_t* o1)
{
  uint32_t ks0 = k0, ks1 = k1, ks2 = k0 ^ k1 ^ 0x1BD11BDAu;
  x0 += ks0; x1 += ks1;
#define TFR(r) { x0 += x1; x1 = (x1 << (r)) | (x1 >> (32-(r))); x1 ^= x0; }
  TFR(13) TFR(15) TFR(26) TFR(6)   x0 += ks1; x1 += ks2 + 1u;
  TFR(17) TFR(29) TFR(16) TFR(24)  x0 += ks2; x1 += ks0 + 2u;
  TFR(13) TFR(15) TFR(26) TFR(6)   x0 += ks0; x1 += ks1 + 3u;
  TFR(17) TFR(29) TFR(16) TFR(24)  x0 += ks1; x1 += ks2 + 4u;
  TFR(13) TFR(15) TFR(26) TFR(6)   x0 += ks2; x1 += ks0 + 5u;
#undef TFR
  *o0 = x0; *o1 = x1;
}

__device__ __forceinline__ float bfu(unsigned short u){
  return __uint_as_float(((unsigned int)u) << 16);
}
__device__ __forceinline__ unsigned short f2bf(float f){  // RNE
  unsigned int u = __float_as_uint(f);
  u += 0x7fffu + ((u >> 16) & 1u);
  return (unsigned short)(u >> 16);
}

// bf16 transposed weight layout (ushort offsets): WtIn[128][64], WtC0[128][128], WtC1[128][128]
#define WT_IN  0
#define WT_C0  8192
#define WT_C1  24576
#define WT_TOT 40960

// ---- prep: zero cnt  +  build bf16 transposed weights straight from f32 inputs ----
// (dtype flags removed: all inputs proven f32 across rounds 3-14)
__global__ __launch_bounds__(256) void k_prep(int* __restrict__ cnt, int zb, int N,
    const float* __restrict__ W_in, const float* __restrict__ Wc,
    unsigned short* __restrict__ wt)
{
  int b = blockIdx.x;
  if (b < zb){
    int i = b*256 + threadIdx.x;
    if (i < N) cnt[i] = 0;
  } else {
    int idx = (b - zb)*256 + threadIdx.x;
    if (idx >= WT_TOT) return;
    if (idx < WT_C0){                 // WtIn[n][k] = W_in[k][n], n<128, k<64
      int n = idx >> 6, k = idx & 63;
      wt[idx] = f2bf(W_in[k*128 + n]);
    } else if (idx < WT_C1){          // WtC0[n][k] = Wc0[k][n]
      int r = idx - WT_C0; int n = r >> 7, k = r & 127;
      wt[idx] = f2bf(Wc[k*128 + n]);
    } else {                          // WtC1[n][k] = Wc1[k][n]
      int r = idx - WT_C1; int n = r >> 7, k = r & 127;
      wt[idx] = f2bf(Wc[16384 + k*128 + n]);
    }
  }
}

// ---------------- CSR build ----------------
__global__ __launch_bounds__(256) void k_count(const int* __restrict__ dst, int* __restrict__ cnt,
                                               int* __restrict__ perm, int E){
  int e = blockIdx.x*256 + threadIdx.x;
  if (e < E){
    int p = atomicAdd(&cnt[dst[e]], 1);
    perm[e] = p;
  }
}
__global__ __launch_bounds__(256) void k_scan1(const int* __restrict__ cnt, int* __restrict__ bsum, int N){
  int tid = threadIdx.x;
  int base = blockIdx.x*1024 + tid*4;
  int s = 0;
  #pragma unroll
  for (int j=0;j<4;++j){ int idx = base+j; if (idx < N) s += cnt[idx]; }
  __shared__ int sh[256];
  sh[tid] = s; __syncthreads();
  for (int o=128;o;o>>=1){ if (tid<o) sh[tid]+=sh[tid+o]; __syncthreads(); }
  if (tid==0) bsum[blockIdx.x] = sh[0];
}
__global__ __launch_bounds__(64) void k_scan2(const int* __restrict__ bsum, int* __restrict__ boff,
                                              int nb, int* __restrict__ rowptr, int N){
  if (threadIdx.x==0 && blockIdx.x==0){
    int run = 0;
    for (int b=0;b<nb;++b){ boff[b]=run; run += bsum[b]; }
    rowptr[N] = run;   // == E
  }
}
__global__ __launch_bounds__(256) void k_scan3(const int* __restrict__ cnt, const int* __restrict__ boff,
                                               int* __restrict__ rowptr, float* __restrict__ dinv, int N){
  int tid = threadIdx.x;
  int base = blockIdx.x*1024 + tid*4;
  int a[4]; int tsum = 0;
  #pragma unroll
  for (int j=0;j<4;++j){ int idx=base+j; a[j] = (idx < N) ? cnt[idx] : 0; tsum += a[j]; }
  __shared__ int sh[256];
  sh[tid] = tsum; __syncthreads();
  for (int off=1; off<256; off<<=1){
    int v = 0; if (tid>=off) v = sh[tid-off];
    __syncthreads(); sh[tid] += v; __syncthreads();
  }
  int run = boff[blockIdx.x] + (sh[tid] - tsum);
  #pragma unroll
  for (int j=0;j<4;++j){
    int idx=base+j;
    if (idx < N){
      rowptr[idx] = run;
      dinv[idx] = 1.0f / sqrtf(1.0f + (float)a[j]);
    }
    run += a[j];
  }
}
// R15: CSR entry = (src byte-offset, fused coefficient dinv[src]*dinv[dst])
__global__ __launch_bounds__(256) void k_fill(const int* __restrict__ src, const int* __restrict__ dst,
                                              const int* __restrict__ rowptr, const int* __restrict__ perm,
                                              const float* __restrict__ dinv,
                                              int2* __restrict__ csr2, int E){
  int e = blockIdx.x*256 + threadIdx.x;
  if (e < E){
    int d = dst[e];
    int s = src[e];
    float cf = dinv[s]*dinv[d];
    csr2[rowptr[d] + perm[e]] = make_int2(s << 8, __float_as_int(cf));  // s*256 bytes (H_DIM*2)
  }
}

// ------- MFMA GEMM: C[M,128] = A[M,K] @ B[K,128], f32 accum; Bt transposed bf16.
// EXT=true: A is f32 (the network input x); else bf16 activations. -------
template<int K, bool EXT, bool RELUBIAS>
__global__ __launch_bounds__(256) void gemm_mfma(const void* __restrict__ Av,
    const unsigned short* __restrict__ Bt, const float* __restrict__ bias,
    unsigned short* __restrict__ C, int M)
{
  const int tid  = threadIdx.x;
  const int wid  = tid >> 6;
  const int lane = tid & 63;
  const int l15  = lane & 15;
  const int quad = lane >> 4;
  const int rowBase = blockIdx.x * 64;
  const int col0 = wid * 32;

  f32x4 acc[4][2];
  #pragma unroll
  for (int mt=0;mt<4;++mt)
    #pragma unroll
    for (int nt=0;nt<2;++nt) acc[mt][nt] = (f32x4){0.f,0.f,0.f,0.f};

  #pragma unroll
  for (int k0 = 0; k0 < K; k0 += 32){
    bf16x8 bf[2];
    #pragma unroll
    for (int nt=0;nt<2;++nt)
      bf[nt] = *(const bf16x8*)(Bt + (size_t)(col0 + nt*16 + l15)*K + k0 + quad*8);
    #pragma unroll
    for (int mt=0;mt<4;++mt){
      int r = rowBase + mt*16 + l15;
      if (r >= M) r = M-1;             // clamped load; store is guarded
      bf16x8 af;
      if (!EXT){
        af = *(const bf16x8*)((const unsigned short*)Av + (size_t)r*K + k0 + quad*8);
      } else {
        const float* ap = (const float*)Av + (size_t)r*K + k0 + quad*8;
        #pragma unroll
        for (int j=0;j<8;++j) ((unsigned short*)&af)[j] = f2bf(ap[j]);
      }
      #pragma unroll
      for (int nt=0;nt<2;++nt)
        acc[mt][nt] = __builtin_amdgcn_mfma_f32_16x16x32_bf16(af, bf[nt], acc[mt][nt], 0,0,0);
    }
  }

  #pragma unroll
  for (int mt=0;mt<4;++mt){
    #pragma unroll
    for (int nt=0;nt<2;++nt){
      int col = col0 + nt*16 + l15;
      float bb = 0.f;
      if (RELUBIAS) bb = bias[col];
      #pragma unroll
      for (int reg=0;reg<4;++reg){
        int row = rowBase + mt*16 + quad*4 + reg;
        if (row < M){
          float vv = acc[mt][nt][reg];
          if (RELUBIAS) vv = fmaxf(vv + bb, 0.f);
          C[(size_t)row*128 + col] = f2bf(vv);
        }
      }
    }
  }
}

// ---- gather (R15: csr2 carries byte-offset + fused coef; minimal per-edge VALU) ----
__global__ __launch_bounds__(256) void gcn_gather(const unsigned short* __restrict__ t,
    const int* __restrict__ rowptr, const int2* __restrict__ csr2,
    const float* __restrict__ dinv, const float* __restrict__ bcw,
    unsigned short* __restrict__ v, double* __restrict__ part, int N)
{
  int node = (int)((blockIdx.x*256u + threadIdx.x) >> 6);
  int lane = threadIdx.x & 63;
  const char* tl = (const char*)t + lane*4;
  float ls = 0.f, lss = 0.f;
  if (node < N){
    float dn = dinv[node];
    unsigned int tv = *(const unsigned int*)(tl + ((size_t)node << 8));
    float ax = __uint_as_float(tv<<16), ay = __uint_as_float(tv & 0xffff0000u);
    float dn2 = dn*dn;
    ax *= dn2; ay *= dn2;
    int e0 = rowptr[node], e1 = rowptr[node+1];
    int e = e0;
    for (; e + 8 <= e1; e += 8){
      int2 p[8];
      #pragma unroll
      for (int q=0;q<8;++q) p[q] = csr2[e+q];
      unsigned int rv[8];
      #pragma unroll
      for (int q=0;q<8;++q) rv[q] = *(const unsigned int*)(tl + (unsigned int)p[q].x);
      #pragma unroll
      for (int q=0;q<8;++q){
        float c = __int_as_float(p[q].y);
        ax = fmaf(__uint_as_float(rv[q]<<16),           c, ax);
        ay = fmaf(__uint_as_float(rv[q] & 0xffff0000u), c, ay);
      }
    }
    for (; e < e1; ++e){
      int2 p = csr2[e];
      float c = __int_as_float(p.y);
      unsigned int sv = *(const unsigned int*)(tl + (unsigned int)p.x);
      ax = fmaf(__uint_as_float(sv<<16),           c, ax);
      ay = fmaf(__uint_as_float(sv & 0xffff0000u), c, ay);
    }
    ax += bcw[2*lane]; ay += bcw[2*lane+1];
    unsigned int pk = (unsigned int)f2bf(ax) | ((unsigned int)f2bf(ay) << 16);
    *(unsigned int*)((char*)v + ((size_t)node << 8) + lane*4) = pk;
    ls  = ax + ay;
    lss = ax*ax + ay*ay;
  }
  for (int off=32; off; off>>=1){ ls += __shfl_down(ls, off); lss += __shfl_down(lss, off); }
  __shared__ float ssum[4], ssq[4];
  int wv = threadIdx.x >> 6;
  if (lane==0){ ssum[wv]=ls; ssq[wv]=lss; }
  __syncthreads();
  if (threadIdx.x==0){
    part[2*blockIdx.x]   = (double)(ssum[0]+ssum[1]+ssum[2]+ssum[3]);
    part[2*blockIdx.x+1] = (double)(ssq[0]+ssq[1]+ssq[2]+ssq[3]);
  }
}

// ---- reduce per-block partials -> red[0..1] (single block) ----
__global__ __launch_bounds__(256) void k_reduce(const double* __restrict__ part,
                                                int nblocks, double* __restrict__ red){
  int tid = threadIdx.x;
  double s = 0.0, q = 0.0;
  for (int i = tid; i < nblocks; i += 256){
    s += part[2*i];
    q += part[2*i+1];
  }
  __shared__ double shs[256], shq[256];
  shs[tid] = s; shq[tid] = q; __syncthreads();
  for (int o=128;o;o>>=1){
    if (tid<o){ shs[tid]+=shs[tid+o]; shq[tid]+=shq[tid+o]; }
    __syncthreads();
  }
  if (tid==0){ red[0]=shs[0]; red[1]=shq[0]; }
}

// -------- LayerNorm(graph) + ReLU + dropout (partitionable threefry, XOR-fold — VERIFIED R10) --------
__global__ __launch_bounds__(256) void ln_relu_drop(const unsigned short* __restrict__ v,
    unsigned short* __restrict__ h, const double* __restrict__ red,
    const float* __restrict__ gammaf, const float* __restrict__ betaf,
    uint32_t k0, uint32_t k1, int total, double tot)
{
  int j = blockIdx.x*256 + threadIdx.x;
  if (j >= total) return;
  double S = red[0], Q = red[1];
  double mu_d = S / tot;
  double var_d = Q / tot - mu_d*mu_d;
  if (var_d < 0.0) var_d = 0.0;
  float mu  = (float)mu_d;
  float inv = 1.0f / ((float)sqrt(var_d) + 1e-5f);

  uint32_t b0, b1;
  tf2x32(k0, k1, 0u, (uint32_t)j, &b0, &b1);   // counter hi=0, lo=j
  uint32_t bits = b0 ^ b1;                     // xor-fold (verified)
  float u = __uint_as_float((bits >> 9) | 0x3f800000u) - 1.0f;

  int c = j & (H_DIM-1);
  float y = fmaf((bfu(v[j]) - mu)*inv, gammaf[c], betaf[c]);
  y = fmaxf(y, 0.f);
  h[j] = f2bf((u < 0.8f) ? (y / 0.8f) : 0.f);
}

// ---------------- out = softmax(h @ W_out + b_out) -> f32 ----------------
__global__ __launch_bounds__(256) void out_softmax(const unsigned short* __restrict__ h,
    const float* __restrict__ Wo, const float* __restrict__ bo,
    float2* __restrict__ outv, int N)
{
  int node = (int)((blockIdx.x*256u + threadIdx.x) >> 6);
  int lane = threadIdx.x & 63;
  if (node >= N) return;
  unsigned int hv = ((const unsigned int*)(h + (size_t)node*H_DIM))[lane];
  float h0 = __uint_as_float(hv<<16), h1 = __uint_as_float(hv & 0xffff0000u);
  float4 wq = ((const float4*)Wo)[lane];
  float d0 = h0*wq.x + h1*wq.z;
  float d1 = h0*wq.y + h1*wq.w;
  for (int off=32; off; off>>=1){ d0 += __shfl_down(d0, off); d1 += __shfl_down(d1, off); }
  if (lane==0){
    d0 += bo[0]; d1 += bo[1];
    float m = fmaxf(d0, d1);
    float e0 = expf(d0 - m), e1 = expf(d1 - m);
    float s = e0 + e1;
    outv[node] = make_float2(e0/s, e1/s);
  }
}

// ---------------- launch ----------------
extern "C" void kernel_launch(void* const* d_in, const int* in_sizes, int n_in,
                              void* d_out, int out_size, void* d_ws, size_t ws_size,
                              hipStream_t stream) {
  (void)n_in; (void)out_size; (void)ws_size;
  const int N = in_sizes[0] / D_IN;     // x is [N, 64]
  const int E = in_sizes[1] / 2;        // edge_index is [2, E]
  const int total = N * H_DIM;
  const double tot = (double)total;

  const float* x    = (const float*)d_in[0];
  const int*   ei   = (const int*)d_in[1];
  const float* W_in = (const float*)d_in[2];
  const float* b_in = (const float*)d_in[3];
  const float* Wc   = (const float*)d_in[4];
  const float* bc   = (const float*)d_in[5];
  const float* gam  = (const float*)d_in[6];
  const float* bet  = (const float*)d_in[7];
  const float* W_o  = (const float*)d_in[8];
  const float* b_o  = (const float*)d_in[9];
  const int* src = ei;
  const int* dst = ei + E;
  char* ws = (char*)d_ws;

  const int nb = (N + 1023) >> 10;      // scan blocks
  const int nodeBlocks = (N + 3) / 4;   // 64 lanes per node
  const int zb = (N + 255) / 256;

  // runtime workspace layout, 256B-aligned slabs (~72 MB)
  size_t o = 0;
  auto take = [&](size_t bytes)->char*{ char* p = ws + o; o = (o + bytes + 255) & ~(size_t)255; return p; };
  double* red    = (double*)take(4*sizeof(double));
  double* part   = (double*)take((size_t)nodeBlocks*2*sizeof(double));
  float*  dinv   = (float*) take((size_t)N*4);
  int*    cnt    = (int*)   take((size_t)N*4);
  int*    rowptr = (int*)   take(((size_t)N+1)*4);
  int*    bsum   = (int*)   take((size_t)nb*4);
  int*    boff   = (int*)   take((size_t)nb*4);
  unsigned short* wt = (unsigned short*)take((size_t)WT_TOT*2);
  int2*   csr2   = (int2*)  take((size_t)E*8);
  int*    perm   = (int*)   take((size_t)E*4);
  unsigned short* actA = (unsigned short*)take((size_t)total*2);
  unsigned short* actB = (unsigned short*)take((size_t)total*2);

  // fold_in(key(1), i) = tf2x32(key=(0,1), counter=[0,i]) — verified
  uint32_t k00,k01,k10,k11;
  tf2x32(0u,1u,0u,0u,&k00,&k01);
  tf2x32(0u,1u,0u,1u,&k10,&k11);

  k_prep  <<<zb + (WT_TOT+255)/256, 256,0,stream>>>(cnt, zb, N, W_in, Wc, wt);
  k_count <<<(E+255)/256,256,0,stream>>>(dst, cnt, perm, E);
  k_scan1 <<<nb,  256,0,stream>>>(cnt, bsum, N);
  k_scan2 <<<1,    64,0,stream>>>(bsum, boff, nb, rowptr, N);
  k_scan3 <<<nb,  256,0,stream>>>(cnt, boff, rowptr, dinv, N);
  k_fill  <<<(E+255)/256,256,0,stream>>>(src, dst, rowptr, perm, dinv, csr2, E);

  const int gemmBlocks = (N + 63) / 64;
  const int fullBlocks = (total + 255) / 256;

  // A <- relu(x @ W_in + b_in)   [MFMA, f32 A]
  gemm_mfma<64,true,true><<<gemmBlocks,256,0,stream>>>(x, wt+WT_IN, b_in, actA, N);

  // layer 0
  gemm_mfma<128,false,false><<<gemmBlocks,256,0,stream>>>(actA, wt+WT_C0, nullptr, actB, N);
  gcn_gather<<<nodeBlocks,256,0,stream>>>(actB, rowptr, csr2, dinv, bc, actA, part, N);
  k_reduce<<<1,256,0,stream>>>(part, nodeBlocks, red);
  ln_relu_drop<<<fullBlocks,256,0,stream>>>(actA, actB, red, gam, bet, k00, k01, total, tot);

  // layer 1
  gemm_mfma<128,false,false><<<gemmBlocks,256,0,stream>>>(actB, wt+WT_C1, nullptr, actA, N);
  gcn_gather<<<nodeBlocks,256,0,stream>>>(actA, rowptr, csr2, dinv, bc + 128, actB, part, N);
  k_reduce<<<1,256,0,stream>>>(part, nodeBlocks, red+2);
  ln_relu_drop<<<fullBlocks,256,0,stream>>>(actB, actA, red+2, gam + 128, bet + 128, k10, k11, total, tot);

  // out (f32)
  out_softmax<<<nodeBlocks,256,0,stream>>>(actA, W_o, b_o, (float2*)d_out, N);
}